// Round 2
// baseline (953.644 us; speedup 1.0000x reference)
//
#include <hip/hip_runtime.h>
#include <hip/hip_bf16.h>
#include <math.h>

// Problem: B=2, S=2048, D=4096, H=32, KV=8, HD=128, N_REP=4, theta=1e6
// Output fp32 (2,2048,4096).

typedef __bf16 bf16;
typedef __attribute__((ext_vector_type(8))) __bf16 bf16x8;
typedef __attribute__((ext_vector_type(4))) float f32x4;

// async global->LDS, 16 B per lane; LDS dest = wave-uniform base + lane*16
__device__ __forceinline__ void glds16(const void* g, void* l) {
    __builtin_amdgcn_global_load_lds(
        (const __attribute__((address_space(1))) void*)g,
        (__attribute__((address_space(3))) void*)l, 16, 0, 0);
}

// ---------------------------------------------------------------------------
// fp32 -> bf16 elementwise convert (hidden), 8 elems/thread
// ---------------------------------------------------------------------------
__global__ __launch_bounds__(256) void convert_kernel(
    const float* __restrict__ in, bf16* __restrict__ out)
{
    const size_t i0 = ((size_t)blockIdx.x * 256 + threadIdx.x) * 8;
    const float4 a = *(const float4*)(in + i0);
    const float4 b = *(const float4*)(in + i0 + 4);
    bf16x8 p;
    p[0] = (bf16)a.x; p[1] = (bf16)a.y; p[2] = (bf16)a.z; p[3] = (bf16)a.w;
    p[4] = (bf16)b.x; p[5] = (bf16)b.y; p[6] = (bf16)b.z; p[7] = (bf16)b.w;
    *(bf16x8*)(out + i0) = p;
}

// ---------------------------------------------------------------------------
// Weight transpose + fp32->bf16: in [K=4096][N] row-major -> out [N][4096].
// ---------------------------------------------------------------------------
__global__ __launch_bounds__(256) void transpose_conv_kernel(
    const float* __restrict__ in, bf16* __restrict__ out, int N)
{
    __shared__ bf16 tile[32 * 68];
    const int n0 = blockIdx.x * 32, k0 = blockIdx.y * 64;
    const int t = threadIdx.x;
    const int nn = t & 31, kk0 = (t >> 5) * 8;
#pragma unroll
    for (int j = 0; j < 8; ++j)
        tile[nn * 68 + kk0 + j] = (bf16)in[(size_t)(k0 + kk0 + j) * N + n0 + nn];
    __syncthreads();
    const int n2 = t >> 3, c = (t & 7) * 8;
    *(bf16x8*)(out + (size_t)(n0 + n2) * 4096 + k0 + c) = *(const bf16x8*)(&tile[n2 * 68 + c]);
}

// ---------------------------------------------------------------------------
// GEMM m97-style: C[4096,N] = A[4096,4096] * B^T[N][4096] (+bias).
// Tile 128x128, BK=32, 4 waves (2x2), wave 64x64 (4x4 MFMAs), glds staging.
// EPI 0: bias + q->[b,s,h,d], k/v scattered ->[b,kv,s,d] (bf16)
// EPI 1: fp32 out.  AF32: A staged from fp32 via VALU (fallback path only).
// ---------------------------------------------------------------------------
template <int EPI, int AF32>
__global__ __launch_bounds__(256) void gemm_kernel(
    const float* __restrict__ A_f32, const bf16* __restrict__ A_bf16,
    const bf16* __restrict__ BqT, const bf16* __restrict__ BkT, const bf16* __restrict__ BvT,
    const float* __restrict__ b_q, const float* __restrict__ b_k, const float* __restrict__ b_v,
    bf16* __restrict__ q_out, bf16* __restrict__ kv_k, bf16* __restrict__ kv_v,
    float* __restrict__ f_out)
{
    constexpr int LDA = AF32 ? 34 : 32;
    __shared__ bf16 As[128 * LDA];
    __shared__ bf16 Bs[128 * 32];

    const int nt = blockIdx.x, mt = blockIdx.y;
    const int tid = threadIdx.x;
    const int wave = tid >> 6, lane = tid & 63;
    const int l15 = lane & 15, quad = lane >> 4;
    const int wm = (wave >> 1) * 64, wn = (wave & 1) * 64;

    const bf16* BT;
    const float* bias = nullptr;
    int sel = 0, ncol0;
    if (EPI == 0) {
        if (nt < 32)      { BT = BqT; bias = b_q; sel = 0; ncol0 = nt * 128; }
        else if (nt < 40) { BT = BkT; bias = b_k; sel = 1; ncol0 = (nt - 32) * 128; }
        else              { BT = BvT; bias = b_v; sel = 2; ncol0 = (nt - 40) * 128; }
    } else {
        BT = BqT; ncol0 = nt * 128;
    }
    const int row0 = mt * 128;

    const f32x4 vzero = {0.f, 0.f, 0.f, 0.f};
    f32x4 acc[4][4];
#pragma unroll
    for (int mi = 0; mi < 4; ++mi)
#pragma unroll
        for (int ni = 0; ni < 4; ++ni) acc[mi][ni] = vzero;

    const int a_row = tid >> 1, a_seg = (tid & 1) * 16;   // AF32 VALU staging
    const int g_row = lane >> 2, g_seg = (lane & 3) * 8;  // glds lane mapping

    for (int k0 = 0; k0 < 4096; k0 += 32) {
        // ---- stage A tile (128x32) ----
        if (AF32) {
            const float4* src = (const float4*)(A_f32 + (size_t)(row0 + a_row) * 4096 + k0 + a_seg);
            float4 f0 = src[0], f1 = src[1], f2 = src[2], f3 = src[3];
            bf16x8 p0, p1;
            p0[0] = (bf16)f0.x; p0[1] = (bf16)f0.y; p0[2] = (bf16)f0.z; p0[3] = (bf16)f0.w;
            p0[4] = (bf16)f1.x; p0[5] = (bf16)f1.y; p0[6] = (bf16)f1.z; p0[7] = (bf16)f1.w;
            p1[0] = (bf16)f2.x; p1[1] = (bf16)f2.y; p1[2] = (bf16)f2.z; p1[3] = (bf16)f2.w;
            p1[4] = (bf16)f3.x; p1[5] = (bf16)f3.y; p1[6] = (bf16)f3.z; p1[7] = (bf16)f3.w;
            *(bf16x8*)(&As[a_row * LDA + a_seg]) = p0;
            *(bf16x8*)(&As[a_row * LDA + a_seg + 8]) = p1;
        } else {
#pragma unroll
            for (int c = 0; c < 2; ++c)
                glds16(A_bf16 + (size_t)(row0 + wave * 32 + c * 16 + g_row) * 4096 + k0 + g_seg,
                       &As[(wave * 32 + c * 16) * 32]);
        }
        // ---- stage B^T tile (128 n-rows x 32 k) via glds ----
#pragma unroll
        for (int c = 0; c < 2; ++c)
            glds16(BT + (size_t)(ncol0 + wave * 32 + c * 16 + g_row) * 4096 + k0 + g_seg,
                   &Bs[(wave * 32 + c * 16) * 32]);
        __syncthreads();

        bf16x8 af[4], bfv[4];
#pragma unroll
        for (int mi = 0; mi < 4; ++mi)
            af[mi] = *(const bf16x8*)(&As[(wm + mi * 16 + l15) * LDA + quad * 8]);
#pragma unroll
        for (int ni = 0; ni < 4; ++ni)
            bfv[ni] = *(const bf16x8*)(&Bs[(wn + ni * 16 + l15) * 32 + quad * 8]);
#pragma unroll
        for (int mi = 0; mi < 4; ++mi)
#pragma unroll
            for (int ni = 0; ni < 4; ++ni)
                acc[mi][ni] = __builtin_amdgcn_mfma_f32_16x16x32_bf16(af[mi], bfv[ni], acc[mi][ni], 0, 0, 0);
        __syncthreads();
    }

    // ---- epilogue: C row = quad*4+reg, col = l15 ----
#pragma unroll
    for (int mi = 0; mi < 4; ++mi)
#pragma unroll
        for (int ni = 0; ni < 4; ++ni)
#pragma unroll
            for (int i = 0; i < 4; ++i) {
                const int gr = row0 + wm + mi * 16 + quad * 4 + i;
                const int gc = ncol0 + wn + ni * 16 + l15;
                float vv = acc[mi][ni][i];
                if (EPI == 1) {
                    f_out[(size_t)gr * 4096 + gc] = vv;
                } else {
                    vv += bias[gc];
                    if (sel == 0) {
                        q_out[(size_t)gr * 4096 + gc] = (bf16)vv;  // [b,s,h,d]
                    } else {
                        bf16* dst = (sel == 1) ? kv_k : kv_v;      // [b,kv,s,d]
                        dst[(size_t)((gr >> 11) * 8 + (gc >> 7)) * 262144 +
                            (size_t)(gr & 2047) * 128 + (gc & 127)] = (bf16)vv;
                    }
                }
            }
}

// ---------------------------------------------------------------------------
// In-place RoPE. Q [b,s,h,128] (scale folded); K [b,kv,s,128].
// ---------------------------------------------------------------------------
__global__ __launch_bounds__(256) void rope_q_kernel(
    bf16* __restrict__ q, const int* __restrict__ pos_ids)
{
    const int idx = blockIdx.x * 256 + threadIdx.x;
    const int d = idx & 63, h = (idx >> 6) & 31, tok = idx >> 11;
    const float posv = (float)pos_ids[tok];
    const float fr = exp2f((float)d * (-19.931568569324174f / 64.f));
    float sn, cs;
    sincosf(posv * fr, &sn, &cs);
    bf16* xp = q + (size_t)tok * 4096 + h * 128 + d;
    const float x1 = (float)xp[0], x2 = (float)xp[64];
    const float scale = 0.08838834764831845f;
    xp[0]  = (bf16)((x1 * cs - x2 * sn) * scale);
    xp[64] = (bf16)((x1 * sn + x2 * cs) * scale);
}

__global__ __launch_bounds__(256) void rope_k_kernel(
    bf16* __restrict__ k, const int* __restrict__ pos_ids)
{
    const int idx = blockIdx.x * 256 + threadIdx.x;
    const int d = idx & 63, s = (idx >> 6) & 2047, bk = idx >> 17;
    const int b = bk >> 3;
    const float posv = (float)pos_ids[b * 2048 + s];
    const float fr = exp2f((float)d * (-19.931568569324174f / 64.f));
    float sn, cs;
    sincosf(posv * fr, &sn, &cs);
    bf16* xp = k + ((size_t)bk * 2048 + s) * 128 + d;
    const float x1 = (float)xp[0], x2 = (float)xp[64];
    xp[0]  = (bf16)(x1 * cs - x2 * sn);
    xp[64] = (bf16)(x1 * sn + x2 * cs);
}

// ---------------------------------------------------------------------------
// Flash attention, causal, GQA. 4 waves, wave owns 32 q-rows (2 m-tiles).
// KV tiles of 64, balanced q-tile pairs (pair, 15-pair): 34 steps/block.
//
// R1 pipeline: K/V double-buffered in LDS with async-STAGE split (T14):
//  - issue global loads for tile t+1 into regs BEFORE computing tile t
//  - write regs -> alternate LDS buffer AFTER compute
//  - ONE barrier per step (dbuf makes write-other-buffer race-free)
//  - flattened 34-step loop (K/V base identical for both phases; only
//    Q frags + accumulators reset at the phase boundary -> no pipe drain)
// Strides chosen for 2-way (free) bank aliasing on b128 fragment reads:
//  K stride 138 (bank = 5*l15+4q), V 70 (3*l15+4q), P 70.  LDS ~80 KB,
//  2 blocks/CU (= grid residency cap already).  setprio(1) around MFMA.
// ---------------------------------------------------------------------------
__global__ __launch_bounds__(256) void attn_kernel(
    const bf16* __restrict__ q, const bf16* __restrict__ k,
    const bf16* __restrict__ v, bf16* __restrict__ o)
{
    constexpr int KSTR = 138, VSTR = 70, PSTR = 70;
    __shared__ bf16 Ksl[2][64 * KSTR];    // [buf][kv][d]
    __shared__ bf16 Vsl[2][128 * VSTR];   // [buf][d][kv]
    __shared__ bf16 Psl[4 * 16 * PSTR];   // per-wave [qrow][kv]

    const int pair = blockIdx.x & 7;
    const int h  = (blockIdx.x >> 3) & 31;
    const int b  = blockIdx.x >> 8;
    const int kvh = h >> 2;
    const int tid = threadIdx.x;
    const int wave = tid >> 6, lane = tid & 63;
    const int l15 = lane & 15, quad = lane >> 4;

    const int qt0 = pair, qt1 = 15 - pair;
    const int nT0 = 2 * qt0 + 2, nT = nT0 + 2 * qt1 + 2;   // 34

    const bf16* kbase = k + (size_t)(b * 8 + kvh) * 2048 * 128;
    const bf16* vbase = v + (size_t)(b * 8 + kvh) * 2048 * 128;

    const int kr = tid >> 2, ksg = (tid & 3) * 32;  // K staging: 64 rows x 4 segs
    const f32x4 vzero = {0.f, 0.f, 0.f, 0.f};

    bf16x8 qf[2][4];
    f32x4 acc_o[2][8];
    float m_i[2][4], l_i[2][4];
    int qbase = qt0 * 128 + wave * 32;

    auto load_q = [&](int qt) {
        const int qb = qt * 128 + wave * 32;
#pragma unroll
        for (int mi = 0; mi < 2; ++mi) {
            const bf16* qrow = q + ((size_t)(b * 2048 + qb + mi * 16 + l15) * 32 + h) * 128;
#pragma unroll
            for (int kb = 0; kb < 4; ++kb)
                qf[mi][kb] = *(const bf16x8*)(qrow + kb * 32 + quad * 8);
        }
    };
    auto reset_state = [&]() {
#pragma unroll
        for (int mi = 0; mi < 2; ++mi) {
#pragma unroll
            for (int i = 0; i < 8; ++i) acc_o[mi][i] = vzero;
#pragma unroll
            for (int i = 0; i < 4; ++i) { m_i[mi][i] = -INFINITY; l_i[mi][i] = 0.f; }
        }
    };
    auto epilogue = [&]() {
#pragma unroll
        for (int mi = 0; mi < 2; ++mi) {
            float inv[4];
#pragma unroll
            for (int i = 0; i < 4; ++i) inv[i] = 1.f / l_i[mi][i];
#pragma unroll
            for (int dn = 0; dn < 8; ++dn)
#pragma unroll
                for (int i = 0; i < 4; ++i) {
                    const int s = qbase + mi * 16 + quad * 4 + i;
                    o[(((size_t)b * 2048 + s) * 32 + h) * 128 + dn * 16 + l15] =
                        (bf16)(acc_o[mi][dn][i] * inv[i]);
                }
        }
    };

    // staging registers (tile t+1 in flight)
    bf16x8 kreg[4], vreg[4];
    auto issue_loads = [&](int kv0) {
        const bf16x8* ks = (const bf16x8*)(kbase + (size_t)(kv0 + kr) * 128 + ksg);
        kreg[0] = ks[0]; kreg[1] = ks[1]; kreg[2] = ks[2]; kreg[3] = ks[3];
        const bf16x8* vs = (const bf16x8*)(vbase + (size_t)(kv0 + lane) * 128 + wave * 32);
        vreg[0] = vs[0]; vreg[1] = vs[1]; vreg[2] = vs[2]; vreg[3] = vs[3];
    };
    auto write_lds = [&](int buf) {
        bf16x8* kd = (bf16x8*)(&Ksl[buf][kr * KSTR + ksg]);
        kd[0] = kreg[0]; kd[1] = kreg[1]; kd[2] = kreg[2]; kd[3] = kreg[3];
#pragma unroll
        for (int i = 0; i < 8; ++i) {
            Vsl[buf][(wave * 32 + i)      * VSTR + lane] = vreg[0][i];
            Vsl[buf][(wave * 32 + 8 + i)  * VSTR + lane] = vreg[1][i];
            Vsl[buf][(wave * 32 + 16 + i) * VSTR + lane] = vreg[2][i];
            Vsl[buf][(wave * 32 + 24 + i) * VSTR + lane] = vreg[3][i];
        }
    };

    // ---- prologue: stage tile 0 into buf 0 ----
    issue_loads(0);
    write_lds(0);
    load_q(qt0);
    reset_state();
    __syncthreads();

    int cur = 0;
    for (int s = 0; s < nT; ++s) {
        // issue global loads for next tile (latency hides under compute)
        if (s + 1 < nT) {
            const int nk = (s + 1 < nT0 ? s + 1 : s + 1 - nT0) * 64;
            issue_loads(nk);
        }
        // phase boundary: flush phase-0 output, reload Q, reset state
        if (s == nT0) {
            epilogue();
            load_q(qt1);
            reset_state();
            qbase = qt1 * 128 + wave * 32;
        }
        const int kv0 = (s < nT0 ? s : s - nT0) * 64;

        if (kv0 <= qbase + 31) {  // wave has unmasked work in this tile
            // ---- S = Q K^T, joint over m-tiles (K frag read once) ----
            f32x4 sacc[2][4];
#pragma unroll
            for (int mi = 0; mi < 2; ++mi)
#pragma unroll
                for (int nt = 0; nt < 4; ++nt) sacc[mi][nt] = vzero;
            __builtin_amdgcn_s_setprio(1);
#pragma unroll
            for (int nt = 0; nt < 4; ++nt)
#pragma unroll
                for (int kb = 0; kb < 4; ++kb) {
                    const bf16x8 kf = *(const bf16x8*)(&Ksl[cur][(nt * 16 + l15) * KSTR + kb * 32 + quad * 8]);
                    sacc[0][nt] = __builtin_amdgcn_mfma_f32_16x16x32_bf16(qf[0][kb], kf, sacc[0][nt], 0, 0, 0);
                    sacc[1][nt] = __builtin_amdgcn_mfma_f32_16x16x32_bf16(qf[1][kb], kf, sacc[1][nt], 0, 0, 0);
                }
            __builtin_amdgcn_s_setprio(0);

            // ---- per-m-tile softmax + P write ----
            bf16x8 pf[2][2];
#pragma unroll
            for (int mi = 0; mi < 2; ++mi) {
                const int rb = qbase + mi * 16;
                if (kv0 + 63 > rb) {  // diagonal tile: apply causal mask
#pragma unroll
                    for (int nt = 0; nt < 4; ++nt) {
                        const int kvc = kv0 + nt * 16 + l15;
#pragma unroll
                        for (int i = 0; i < 4; ++i)
                            if (kvc > rb + quad * 4 + i) sacc[mi][nt][i] = -INFINITY;
                    }
                }
                float mt_[4];
#pragma unroll
                for (int i = 0; i < 4; ++i)
                    mt_[i] = fmaxf(fmaxf(sacc[mi][0][i], sacc[mi][1][i]),
                                   fmaxf(sacc[mi][2][i], sacc[mi][3][i]));
#pragma unroll
                for (int off = 1; off < 16; off <<= 1)
#pragma unroll
                    for (int i = 0; i < 4; ++i)
                        mt_[i] = fmaxf(mt_[i], __shfl_xor(mt_[i], off, 64));

                float alpha[4];
#pragma unroll
                for (int i = 0; i < 4; ++i) {
                    const float mnew = fmaxf(m_i[mi][i], mt_[i]);
                    alpha[i] = __expf(m_i[mi][i] - mnew);
                    m_i[mi][i] = mnew;
                }
                float rs[4] = {0.f, 0.f, 0.f, 0.f};
#pragma unroll
                for (int nt = 0; nt < 4; ++nt)
#pragma unroll
                    for (int i = 0; i < 4; ++i) {
                        const float pv = __expf(sacc[mi][nt][i] - m_i[mi][i]);
                        rs[i] += pv;
                        Psl[wave * (16 * PSTR) + (quad * 4 + i) * PSTR + nt * 16 + l15] = (bf16)pv;
                    }
#pragma unroll
                for (int off = 1; off < 16; off <<= 1)
#pragma unroll
                    for (int i = 0; i < 4; ++i)
                        rs[i] += __shfl_xor(rs[i], off, 64);
#pragma unroll
                for (int i = 0; i < 4; ++i) l_i[mi][i] = l_i[mi][i] * alpha[i] + rs[i];
#pragma unroll
                for (int dn = 0; dn < 8; ++dn)
#pragma unroll
                    for (int i = 0; i < 4; ++i) acc_o[mi][dn][i] *= alpha[i];
                // P -> A-layout frags (wave-local; lgkmcnt orders write->read)
#pragma unroll
                for (int k2 = 0; k2 < 2; ++k2)
                    pf[mi][k2] = *(const bf16x8*)(&Psl[wave * (16 * PSTR) + l15 * PSTR + k2 * 32 + quad * 8]);
            }

            // ---- O += P V, joint over m-tiles (V frag read once) ----
            __builtin_amdgcn_s_setprio(1);
#pragma unroll
            for (int dn = 0; dn < 8; ++dn)
#pragma unroll
                for (int k2 = 0; k2 < 2; ++k2) {
                    const bf16x8 vf = *(const bf16x8*)(&Vsl[cur][(dn * 16 + l15) * VSTR + k2 * 32 + quad * 8]);
                    acc_o[0][dn] = __builtin_amdgcn_mfma_f32_16x16x32_bf16(pf[0][k2], vf, acc_o[0][dn], 0, 0, 0);
                    acc_o[1][dn] = __builtin_amdgcn_mfma_f32_16x16x32_bf16(pf[1][k2], vf, acc_o[1][dn], 0, 0, 0);
                }
            __builtin_amdgcn_s_setprio(0);
        }

        // stage next tile into the other buffer (race-free: different buffer)
        if (s + 1 < nT) write_lds(cur ^ 1);
        __syncthreads();
        cur ^= 1;
    }

    epilogue();
}

// ---------------------------------------------------------------------------
extern "C" void kernel_launch(void* const* d_in, const int* in_sizes, int n_in,
                              void* d_out, int out_size, void* d_ws, size_t ws_size,
                              hipStream_t stream)
{
    (void)in_sizes; (void)n_in; (void)out_size;
    const float* hidden = (const float*)d_in[0];
    const int*   pos    = (const int*)d_in[1];
    const float* wq     = (const float*)d_in[2];
    const float* bq_    = (const float*)d_in[3];
    const float* wk     = (const float*)d_in[4];
    const float* bk_    = (const float*)d_in[5];
    const float* wv     = (const float*)d_in[6];
    const float* bv_    = (const float*)d_in[7];
    const float* wo     = (const float*)d_in[8];
    float* out = (float*)d_out;

    char* ws = (char*)d_ws;
    bf16* wqT   = (bf16*)(ws);                 // 33.5 MB -> attn_o after QKV
    bf16* wkT   = (bf16*)(ws + 33554432);      //  8.4 MB
    bf16* wvT   = (bf16*)(ws + 41943040);      //  8.4 MB
    bf16* q_pre = (bf16*)(ws + 50331648);      // 33.5 MB -> woT after attn
    bf16* k_t   = (bf16*)(ws + 83886080);      //  8.4 MB [b,kv,s,d]
    bf16* v_t   = (bf16*)(ws + 92274688);      //  8.4 MB [b,kv,s,d]
    bf16* hid_b = (bf16*)(ws + 100663296);     // 33.5 MB (if ws allows)
    bf16* attn_o = wqT;
    bf16* woT    = q_pre;
    const bool have_hid = (ws_size >= 134217728);

    // 1) weight transposes (fp32 [K][N] -> bf16 [N][K])
    transpose_conv_kernel<<<dim3(128, 64), 256, 0, stream>>>(wq, wqT, 4096);
    transpose_conv_kernel<<<dim3(32, 64), 256, 0, stream>>>(wk, wkT, 1024);
    transpose_conv_kernel<<<dim3(32, 64), 256, 0, stream>>>(wv, wvT, 1024);

    // 2) QKV projection; K/V written directly to [b,kv,s,d]
    if (have_hid) {
        convert_kernel<<<8192, 256, 0, stream>>>(hidden, hid_b);
        gemm_kernel<0, 0><<<dim3(48, 32), 256, 0, stream>>>(
            nullptr, hid_b, wqT, wkT, wvT, bq_, bk_, bv_, q_pre, k_t, v_t, nullptr);
    } else {
        gemm_kernel<0, 1><<<dim3(48, 32), 256, 0, stream>>>(
            hidden, nullptr, wqT, wkT, wvT, bq_, bk_, bv_, q_pre, k_t, v_t, nullptr);
    }

    // 3) in-place RoPE (Q gets 1/sqrt(128) folded)
    rope_q_kernel<<<32768, 256, 0, stream>>>(q_pre, pos);
    rope_k_kernel<<<8192, 256, 0, stream>>>(k_t, pos);

    // 4) causal GQA flash attention, balanced q-tile pairs -> attn_o [b,s,h,d]
    attn_kernel<<<512, 256, 0, stream>>>(q_pre, k_t, v_t, attn_o);

    // 5) transpose wo into q_pre region (q dead after attn)
    transpose_conv_kernel<<<dim3(128, 64), 256, 0, stream>>>(wo, woT, 4096);

    // 6) output projection -> d_out (fp32)
    gemm_kernel<1, 0><<<dim3(32, 32), 256, 0, stream>>>(
        nullptr, attn_o, woT, nullptr, nullptr, nullptr, nullptr, nullptr,
        nullptr, nullptr, nullptr, out);
}

// Round 3
// 872.455 us; speedup vs baseline: 1.0931x; 1.0931x over previous
//
#include <hip/hip_runtime.h>
#include <hip/hip_bf16.h>
#include <math.h>

// Problem: B=2, S=2048, D=4096, H=32, KV=8, HD=128, N_REP=4, theta=1e6
// Output fp32 (2,2048,4096).

typedef __bf16 bf16;
typedef __attribute__((ext_vector_type(8))) __bf16 bf16x8;
typedef __attribute__((ext_vector_type(4))) float f32x4;

// async global->LDS, 16 B per lane; LDS dest = wave-uniform base + lane*16
__device__ __forceinline__ void glds16(const void* g, void* l) {
    __builtin_amdgcn_global_load_lds(
        (const __attribute__((address_space(1))) void*)g,
        (__attribute__((address_space(3))) void*)l, 16, 0, 0);
}

// v_cvt_pk_bf16_f32: dst.lo = bf16(lo), dst.hi = bf16(hi)  (no builtin; T12)
__device__ __forceinline__ unsigned cvt_pk_bf16(float lo, float hi) {
    unsigned r;
    asm("v_cvt_pk_bf16_f32 %0, %1, %2" : "=v"(r) : "v"(lo), "v"(hi));
    return r;
}

// ---------------------------------------------------------------------------
// fp32 -> bf16 elementwise convert (hidden), 8 elems/thread
// ---------------------------------------------------------------------------
__global__ __launch_bounds__(256) void convert_kernel(
    const float* __restrict__ in, bf16* __restrict__ out)
{
    const size_t i0 = ((size_t)blockIdx.x * 256 + threadIdx.x) * 8;
    const float4 a = *(const float4*)(in + i0);
    const float4 b = *(const float4*)(in + i0 + 4);
    bf16x8 p;
    p[0] = (bf16)a.x; p[1] = (bf16)a.y; p[2] = (bf16)a.z; p[3] = (bf16)a.w;
    p[4] = (bf16)b.x; p[5] = (bf16)b.y; p[6] = (bf16)b.z; p[7] = (bf16)b.w;
    *(bf16x8*)(out + i0) = p;
}

// ---------------------------------------------------------------------------
// Weight transpose + fp32->bf16: in [K=4096][N] row-major -> out [N][4096].
// ---------------------------------------------------------------------------
__global__ __launch_bounds__(256) void transpose_conv_kernel(
    const float* __restrict__ in, bf16* __restrict__ out, int N)
{
    __shared__ bf16 tile[32 * 68];
    const int n0 = blockIdx.x * 32, k0 = blockIdx.y * 64;
    const int t = threadIdx.x;
    const int nn = t & 31, kk0 = (t >> 5) * 8;
#pragma unroll
    for (int j = 0; j < 8; ++j)
        tile[nn * 68 + kk0 + j] = (bf16)in[(size_t)(k0 + kk0 + j) * N + n0 + nn];
    __syncthreads();
    const int n2 = t >> 3, c = (t & 7) * 8;
    *(bf16x8*)(out + (size_t)(n0 + n2) * 4096 + k0 + c) = *(const bf16x8*)(&tile[n2 * 68 + c]);
}

// ---------------------------------------------------------------------------
// GEMM m97-style: C[4096,N] = A[4096,4096] * B^T[N][4096] (+bias).
// Tile 128x128, BK=32, 4 waves (2x2), wave 64x64 (4x4 MFMAs), glds staging.
// EPI 0: bias + q->[b,s,h,d], k/v scattered ->[b,kv,s,d] (bf16)
// EPI 1: fp32 out.  AF32: A staged from fp32 via VALU (fallback path only).
// ---------------------------------------------------------------------------
template <int EPI, int AF32>
__global__ __launch_bounds__(256) void gemm_kernel(
    const float* __restrict__ A_f32, const bf16* __restrict__ A_bf16,
    const bf16* __restrict__ BqT, const bf16* __restrict__ BkT, const bf16* __restrict__ BvT,
    const float* __restrict__ b_q, const float* __restrict__ b_k, const float* __restrict__ b_v,
    bf16* __restrict__ q_out, bf16* __restrict__ kv_k, bf16* __restrict__ kv_v,
    float* __restrict__ f_out)
{
    constexpr int LDA = AF32 ? 34 : 32;
    __shared__ bf16 As[128 * LDA];
    __shared__ bf16 Bs[128 * 32];

    const int nt = blockIdx.x, mt = blockIdx.y;
    const int tid = threadIdx.x;
    const int wave = tid >> 6, lane = tid & 63;
    const int l15 = lane & 15, quad = lane >> 4;
    const int wm = (wave >> 1) * 64, wn = (wave & 1) * 64;

    const bf16* BT;
    const float* bias = nullptr;
    int sel = 0, ncol0;
    if (EPI == 0) {
        if (nt < 32)      { BT = BqT; bias = b_q; sel = 0; ncol0 = nt * 128; }
        else if (nt < 40) { BT = BkT; bias = b_k; sel = 1; ncol0 = (nt - 32) * 128; }
        else              { BT = BvT; bias = b_v; sel = 2; ncol0 = (nt - 40) * 128; }
    } else {
        BT = BqT; ncol0 = nt * 128;
    }
    const int row0 = mt * 128;

    const f32x4 vzero = {0.f, 0.f, 0.f, 0.f};
    f32x4 acc[4][4];
#pragma unroll
    for (int mi = 0; mi < 4; ++mi)
#pragma unroll
        for (int ni = 0; ni < 4; ++ni) acc[mi][ni] = vzero;

    const int a_row = tid >> 1, a_seg = (tid & 1) * 16;   // AF32 VALU staging
    const int g_row = lane >> 2, g_seg = (lane & 3) * 8;  // glds lane mapping

    for (int k0 = 0; k0 < 4096; k0 += 32) {
        // ---- stage A tile (128x32) ----
        if (AF32) {
            const float4* src = (const float4*)(A_f32 + (size_t)(row0 + a_row) * 4096 + k0 + a_seg);
            float4 f0 = src[0], f1 = src[1], f2 = src[2], f3 = src[3];
            bf16x8 p0, p1;
            p0[0] = (bf16)f0.x; p0[1] = (bf16)f0.y; p0[2] = (bf16)f0.z; p0[3] = (bf16)f0.w;
            p0[4] = (bf16)f1.x; p0[5] = (bf16)f1.y; p0[6] = (bf16)f1.z; p0[7] = (bf16)f1.w;
            p1[0] = (bf16)f2.x; p1[1] = (bf16)f2.y; p1[2] = (bf16)f2.z; p1[3] = (bf16)f2.w;
            p1[4] = (bf16)f3.x; p1[5] = (bf16)f3.y; p1[6] = (bf16)f3.z; p1[7] = (bf16)f3.w;
            *(bf16x8*)(&As[a_row * LDA + a_seg]) = p0;
            *(bf16x8*)(&As[a_row * LDA + a_seg + 8]) = p1;
        } else {
#pragma unroll
            for (int c = 0; c < 2; ++c)
                glds16(A_bf16 + (size_t)(row0 + wave * 32 + c * 16 + g_row) * 4096 + k0 + g_seg,
                       &As[(wave * 32 + c * 16) * 32]);
        }
        // ---- stage B^T tile (128 n-rows x 32 k) via glds ----
#pragma unroll
        for (int c = 0; c < 2; ++c)
            glds16(BT + (size_t)(ncol0 + wave * 32 + c * 16 + g_row) * 4096 + k0 + g_seg,
                   &Bs[(wave * 32 + c * 16) * 32]);
        __syncthreads();

        bf16x8 af[4], bfv[4];
#pragma unroll
        for (int mi = 0; mi < 4; ++mi)
            af[mi] = *(const bf16x8*)(&As[(wm + mi * 16 + l15) * LDA + quad * 8]);
#pragma unroll
        for (int ni = 0; ni < 4; ++ni)
            bfv[ni] = *(const bf16x8*)(&Bs[(wn + ni * 16 + l15) * 32 + quad * 8]);
#pragma unroll
        for (int mi = 0; mi < 4; ++mi)
#pragma unroll
            for (int ni = 0; ni < 4; ++ni)
                acc[mi][ni] = __builtin_amdgcn_mfma_f32_16x16x32_bf16(af[mi], bfv[ni], acc[mi][ni], 0, 0, 0);
        __syncthreads();
    }

    // ---- epilogue: C row = quad*4+reg, col = l15 ----
#pragma unroll
    for (int mi = 0; mi < 4; ++mi)
#pragma unroll
        for (int ni = 0; ni < 4; ++ni)
#pragma unroll
            for (int i = 0; i < 4; ++i) {
                const int gr = row0 + wm + mi * 16 + quad * 4 + i;
                const int gc = ncol0 + wn + ni * 16 + l15;
                float vv = acc[mi][ni][i];
                if (EPI == 1) {
                    f_out[(size_t)gr * 4096 + gc] = vv;
                } else {
                    vv += bias[gc];
                    if (sel == 0) {
                        q_out[(size_t)gr * 4096 + gc] = (bf16)vv;  // [b,s,h,d]
                    } else {
                        bf16* dst = (sel == 1) ? kv_k : kv_v;      // [b,kv,s,d]
                        dst[(size_t)((gr >> 11) * 8 + (gc >> 7)) * 262144 +
                            (size_t)(gr & 2047) * 128 + (gc & 127)] = (bf16)vv;
                    }
                }
            }
}

// ---------------------------------------------------------------------------
// In-place RoPE. Q [b,s,h,128] (scale folded); K [b,kv,s,128].
// ---------------------------------------------------------------------------
__global__ __launch_bounds__(256) void rope_q_kernel(
    bf16* __restrict__ q, const int* __restrict__ pos_ids)
{
    const int idx = blockIdx.x * 256 + threadIdx.x;
    const int d = idx & 63, h = (idx >> 6) & 31, tok = idx >> 11;
    const float posv = (float)pos_ids[tok];
    const float fr = exp2f((float)d * (-19.931568569324174f / 64.f));
    float sn, cs;
    sincosf(posv * fr, &sn, &cs);
    bf16* xp = q + (size_t)tok * 4096 + h * 128 + d;
    const float x1 = (float)xp[0], x2 = (float)xp[64];
    const float scale = 0.08838834764831845f;
    xp[0]  = (bf16)((x1 * cs - x2 * sn) * scale);
    xp[64] = (bf16)((x1 * sn + x2 * cs) * scale);
}

__global__ __launch_bounds__(256) void rope_k_kernel(
    bf16* __restrict__ k, const int* __restrict__ pos_ids)
{
    const int idx = blockIdx.x * 256 + threadIdx.x;
    const int d = idx & 63, s = (idx >> 6) & 2047, bk = idx >> 17;
    const int b = bk >> 3;
    const float posv = (float)pos_ids[b * 2048 + s];
    const float fr = exp2f((float)d * (-19.931568569324174f / 64.f));
    float sn, cs;
    sincosf(posv * fr, &sn, &cs);
    bf16* xp = k + ((size_t)bk * 2048 + s) * 128 + d;
    const float x1 = (float)xp[0], x2 = (float)xp[64];
    xp[0]  = (bf16)(x1 * cs - x2 * sn);
    xp[64] = (bf16)(x1 * sn + x2 * cs);
}

// ---------------------------------------------------------------------------
// Flash attention, causal, GQA. 4 waves, wave owns 32 q-rows (2 m-tiles).
// KV tiles of 64, balanced q-tile pairs (pair, 15-pair): 34 steps/block.
// R1 skeleton (single-buffer, 2 barriers/step = known 270us).
//
// R3: SWAPPED QK^T softmax. sacc = mfma(K,Q) -> C[row=kv=quad*4+i][col=q=l15]:
// each q-row's 64 P values live in 4 lanes (16/lane). Row max/sum = in-lane
// tree + 2 cross-quad shfls (was 4 rounds x 4 regs). m/l/alpha are scalars.
// P packed via v_cvt_pk_bf16_f32 -> 4 ds_write_b64 (was 16 ds_write_b16).
// P-frag reads + PV unchanged (A-frag layout identical); O stays [q][d];
// alpha / 1/l broadcast to O-row layout via width-16 shfl.
// T13 defer-max: skip O-rescale while __all(tmax - m <= 8).
// ---------------------------------------------------------------------------
__global__ __launch_bounds__(256) void attn_kernel(
    const bf16* __restrict__ q, const bf16* __restrict__ k,
    const bf16* __restrict__ v, bf16* __restrict__ o)
{
    __shared__ bf16 Ksl[64 * 136];      // [kv][d]
    __shared__ bf16 Vsl[128 * 72];      // [d][kv]
    __shared__ bf16 Psl[4 * 16 * 68];   // per-wave [qrow][kv]

    const int pair = blockIdx.x & 7;
    const int h  = (blockIdx.x >> 3) & 31;
    const int b  = blockIdx.x >> 8;
    const int kvh = h >> 2;
    const int tid = threadIdx.x;
    const int wave = tid >> 6, lane = tid & 63;
    const int l15 = lane & 15, quad = lane >> 4;

    const bf16* kbase = k + (size_t)(b * 8 + kvh) * 2048 * 128;
    const bf16* vbase = v + (size_t)(b * 8 + kvh) * 2048 * 128;

    const int kr = tid >> 2, ksg = (tid & 3) * 32;  // K staging: 64 rows x 4 segs
    const f32x4 vzero = {0.f, 0.f, 0.f, 0.f};

#pragma unroll 1
    for (int phase = 0; phase < 2; ++phase) {
        const int qt = phase ? (15 - pair) : pair;
        const int qbase = qt * 128 + wave * 32;

        // Q fragments, 2 m-tiles (row=l15, k=quad*8+j)
        bf16x8 qf[2][4];
#pragma unroll
        for (int mi = 0; mi < 2; ++mi) {
            const bf16* qrow = q + ((size_t)(b * 2048 + qbase + mi * 16 + l15) * 32 + h) * 128;
#pragma unroll
            for (int kb = 0; kb < 4; ++kb)
                qf[mi][kb] = *(const bf16x8*)(qrow + kb * 32 + quad * 8);
        }

        f32x4 acc_o[2][8];
#pragma unroll
        for (int mi = 0; mi < 2; ++mi)
#pragma unroll
            for (int i = 0; i < 8; ++i) acc_o[mi][i] = vzero;
        float m_i[2] = {-INFINITY, -INFINITY};   // per-lane state for q = l15 (+mi*16)
        float l_i[2] = {0.f, 0.f};

        const int nT = 2 * qt + 2;
        for (int t = 0; t < nT; ++t) {
            const int kv0 = t * 64;
            // ---- stage K row-major ----
            {
                const bf16x8* ks = (const bf16x8*)(kbase + (size_t)(kv0 + kr) * 128 + ksg);
                bf16x8* kd = (bf16x8*)(&Ksl[kr * 136 + ksg]);
                kd[0] = ks[0]; kd[1] = ks[1]; kd[2] = ks[2]; kd[3] = ks[3];
            }
            // ---- stage V transposed: wave=d-block, lane=kv row ----
            {
                const bf16x8* vs = (const bf16x8*)(vbase + (size_t)(kv0 + lane) * 128 + wave * 32);
                bf16x8 w0 = vs[0], w1 = vs[1], w2 = vs[2], w3 = vs[3];
#pragma unroll
                for (int i = 0; i < 8; ++i) {
                    Vsl[(wave * 32 + i)      * 72 + lane] = w0[i];
                    Vsl[(wave * 32 + 8 + i)  * 72 + lane] = w1[i];
                    Vsl[(wave * 32 + 16 + i) * 72 + lane] = w2[i];
                    Vsl[(wave * 32 + 24 + i) * 72 + lane] = w3[i];
                }
            }
            __syncthreads();

            if (kv0 <= qbase + 31) {  // wave has unmasked work in this tile
                // ---- S^T = K Q^T, joint over m-tiles (K frag read once) ----
                // sacc[mi][nt]: row = kv = nt*16 + quad*4 + i, col = q = mi*16 + l15
                f32x4 sacc[2][4];
#pragma unroll
                for (int mi = 0; mi < 2; ++mi)
#pragma unroll
                    for (int nt = 0; nt < 4; ++nt) sacc[mi][nt] = vzero;
                __builtin_amdgcn_s_setprio(1);
#pragma unroll
                for (int nt = 0; nt < 4; ++nt)
#pragma unroll
                    for (int kb = 0; kb < 4; ++kb) {
                        const bf16x8 kf = *(const bf16x8*)(&Ksl[(nt * 16 + l15) * 136 + kb * 32 + quad * 8]);
                        sacc[0][nt] = __builtin_amdgcn_mfma_f32_16x16x32_bf16(kf, qf[0][kb], sacc[0][nt], 0, 0, 0);
                        sacc[1][nt] = __builtin_amdgcn_mfma_f32_16x16x32_bf16(kf, qf[1][kb], sacc[1][nt], 0, 0, 0);
                    }
                __builtin_amdgcn_s_setprio(0);

                // ---- per-m-tile in-register softmax ----
                bf16x8 pf[2][2];
#pragma unroll
                for (int mi = 0; mi < 2; ++mi) {
                    const int rb = qbase + mi * 16;
                    if (kv0 + 63 > rb) {  // diagonal tile: causal mask
#pragma unroll
                        for (int nt = 0; nt < 4; ++nt) {
                            const int kvr = kv0 + nt * 16 + quad * 4;
#pragma unroll
                            for (int i = 0; i < 4; ++i)
                                if (kvr + i > rb + l15) sacc[mi][nt][i] = -INFINITY;
                        }
                    }
                    // row max: in-lane tree (16 vals) + cross-quad shfls
                    float tm;
                    {
                        f32x4 m4;
#pragma unroll
                        for (int i = 0; i < 4; ++i)
                            m4[i] = fmaxf(fmaxf(sacc[mi][0][i], sacc[mi][1][i]),
                                          fmaxf(sacc[mi][2][i], sacc[mi][3][i]));
                        tm = fmaxf(fmaxf(m4[0], m4[1]), fmaxf(m4[2], m4[3]));
                        tm = fmaxf(tm, __shfl_xor(tm, 16, 64));
                        tm = fmaxf(tm, __shfl_xor(tm, 32, 64));
                    }
                    // T13 defer-max: only rescale when max grew past threshold
                    if (!__all(tm - m_i[mi] <= 8.f)) {
                        const float mnew = fmaxf(m_i[mi], tm);
                        const float alpha = __expf(m_i[mi] - mnew);
                        m_i[mi] = mnew;
                        l_i[mi] *= alpha;
                        float aw[4];
#pragma unroll
                        for (int i = 0; i < 4; ++i)
                            aw[i] = __shfl(alpha, quad * 4 + i, 16);
#pragma unroll
                        for (int dn = 0; dn < 8; ++dn)
#pragma unroll
                            for (int i = 0; i < 4; ++i) acc_o[mi][dn][i] *= aw[i];
                    }
                    // exp + row-sum + pack P
                    float p[4][4];
                    float rs = 0.f;
#pragma unroll
                    for (int nt = 0; nt < 4; ++nt)
#pragma unroll
                        for (int i = 0; i < 4; ++i) {
                            p[nt][i] = __expf(sacc[mi][nt][i] - m_i[mi]);
                            rs += p[nt][i];
                        }
                    rs += __shfl_xor(rs, 16, 64);
                    rs += __shfl_xor(rs, 32, 64);
                    l_i[mi] += rs;
#pragma unroll
                    for (int nt = 0; nt < 4; ++nt) {
                        uint2 w;
                        w.x = cvt_pk_bf16(p[nt][0], p[nt][1]);
                        w.y = cvt_pk_bf16(p[nt][2], p[nt][3]);
                        *(uint2*)(&Psl[wave * 1088 + l15 * 68 + nt * 16 + quad * 4]) = w;
                    }
                    // P -> A-layout frags (wave-local; lgkmcnt orders write->read)
#pragma unroll
                    for (int k2 = 0; k2 < 2; ++k2)
                        pf[mi][k2] = *(const bf16x8*)(&Psl[wave * 1088 + l15 * 68 + k2 * 32 + quad * 8]);
                }

                // ---- O += P V, joint over m-tiles (V frag read once) ----
                __builtin_amdgcn_s_setprio(1);
#pragma unroll
                for (int dn = 0; dn < 8; ++dn)
#pragma unroll
                    for (int k2 = 0; k2 < 2; ++k2) {
                        const bf16x8 vf = *(const bf16x8*)(&Vsl[(dn * 16 + l15) * 72 + k2 * 32 + quad * 8]);
                        acc_o[0][dn] = __builtin_amdgcn_mfma_f32_16x16x32_bf16(pf[0][k2], vf, acc_o[0][dn], 0, 0, 0);
                        acc_o[1][dn] = __builtin_amdgcn_mfma_f32_16x16x32_bf16(pf[1][k2], vf, acc_o[1][dn], 0, 0, 0);
                    }
                __builtin_amdgcn_s_setprio(0);
            }
            __syncthreads();
        }

        // ---- epilogue -> [b,s,h,d]: broadcast 1/l into O-row layout ----
#pragma unroll
        for (int mi = 0; mi < 2; ++mi) {
            const float inv = 1.f / l_i[mi];
            float invw[4];
#pragma unroll
            for (int i = 0; i < 4; ++i)
                invw[i] = __shfl(inv, quad * 4 + i, 16);
#pragma unroll
            for (int dn = 0; dn < 8; ++dn)
#pragma unroll
                for (int i = 0; i < 4; ++i) {
                    const int s = qbase + mi * 16 + quad * 4 + i;
                    o[(((size_t)b * 2048 + s) * 32 + h) * 128 + dn * 16 + l15] =
                        (bf16)(acc_o[mi][dn][i] * invw[i]);
                }
        }
    }
}

// ---------------------------------------------------------------------------
extern "C" void kernel_launch(void* const* d_in, const int* in_sizes, int n_in,
                              void* d_out, int out_size, void* d_ws, size_t ws_size,
                              hipStream_t stream)
{
    (void)in_sizes; (void)n_in; (void)out_size;
    const float* hidden = (const float*)d_in[0];
    const int*   pos    = (const int*)d_in[1];
    const float* wq     = (const float*)d_in[2];
    const float* bq_    = (const float*)d_in[3];
    const float* wk     = (const float*)d_in[4];
    const float* bk_    = (const float*)d_in[5];
    const float* wv     = (const float*)d_in[6];
    const float* bv_    = (const float*)d_in[7];
    const float* wo     = (const float*)d_in[8];
    float* out = (float*)d_out;

    char* ws = (char*)d_ws;
    bf16* wqT   = (bf16*)(ws);                 // 33.5 MB -> attn_o after QKV
    bf16* wkT   = (bf16*)(ws + 33554432);      //  8.4 MB
    bf16* wvT   = (bf16*)(ws + 41943040);      //  8.4 MB
    bf16* q_pre = (bf16*)(ws + 50331648);      // 33.5 MB -> woT after attn
    bf16* k_t   = (bf16*)(ws + 83886080);      //  8.4 MB [b,kv,s,d]
    bf16* v_t   = (bf16*)(ws + 92274688);      //  8.4 MB [b,kv,s,d]
    bf16* hid_b = (bf16*)(ws + 100663296);     // 33.5 MB (if ws allows)
    bf16* attn_o = wqT;
    bf16* woT    = q_pre;
    const bool have_hid = (ws_size >= 134217728);

    // 1) weight transposes (fp32 [K][N] -> bf16 [N][K])
    transpose_conv_kernel<<<dim3(128, 64), 256, 0, stream>>>(wq, wqT, 4096);
    transpose_conv_kernel<<<dim3(32, 64), 256, 0, stream>>>(wk, wkT, 1024);
    transpose_conv_kernel<<<dim3(32, 64), 256, 0, stream>>>(wv, wvT, 1024);

    // 2) QKV projection; K/V written directly to [b,kv,s,d]
    if (have_hid) {
        convert_kernel<<<8192, 256, 0, stream>>>(hidden, hid_b);
        gemm_kernel<0, 0><<<dim3(48, 32), 256, 0, stream>>>(
            nullptr, hid_b, wqT, wkT, wvT, bq_, bk_, bv_, q_pre, k_t, v_t, nullptr);
    } else {
        gemm_kernel<0, 1><<<dim3(48, 32), 256, 0, stream>>>(
            hidden, nullptr, wqT, wkT, wvT, bq_, bk_, bv_, q_pre, k_t, v_t, nullptr);
    }

    // 3) in-place RoPE (Q gets 1/sqrt(128) folded)
    rope_q_kernel<<<32768, 256, 0, stream>>>(q_pre, pos);
    rope_k_kernel<<<8192, 256, 0, stream>>>(k_t, pos);

    // 4) causal GQA flash attention, balanced q-tile pairs -> attn_o [b,s,h,d]
    attn_kernel<<<512, 256, 0, stream>>>(q_pre, k_t, v_t, attn_o);

    // 5) transpose wo into q_pre region (q dead after attn)
    transpose_conv_kernel<<<dim3(128, 64), 256, 0, stream>>>(wo, woT, 4096);

    // 6) output projection -> d_out (fp32)
    gemm_kernel<1, 0><<<dim3(32, 32), 256, 0, stream>>>(
        nullptr, attn_o, woT, nullptr, nullptr, nullptr, nullptr, nullptr,
        nullptr, nullptr, nullptr, out);
}

// Round 4
// 796.743 us; speedup vs baseline: 1.1969x; 1.0950x over previous
//
#include <hip/hip_runtime.h>
#include <hip/hip_bf16.h>
#include <math.h>

// Problem: B=2, S=2048, D=4096, H=32, KV=8, HD=128, N_REP=4, theta=1e6
// Output fp32 (2,2048,4096).

typedef __bf16 bf16;
typedef __attribute__((ext_vector_type(8))) __bf16 bf16x8;
typedef __attribute__((ext_vector_type(4))) float f32x4;

// async global->LDS, 16 B per lane; LDS dest = wave-uniform base + lane*16
__device__ __forceinline__ void glds16(const void* g, void* l) {
    __builtin_amdgcn_global_load_lds(
        (const __attribute__((address_space(1))) void*)g,
        (__attribute__((address_space(3))) void*)l, 16, 0, 0);
}

// v_cvt_pk_bf16_f32: dst.lo = bf16(lo), dst.hi = bf16(hi)  (no builtin; T12)
__device__ __forceinline__ unsigned cvt_pk_bf16(float lo, float hi) {
    unsigned r;
    asm("v_cvt_pk_bf16_f32 %0, %1, %2" : "=v"(r) : "v"(lo), "v"(hi));
    return r;
}

// ---------------------------------------------------------------------------
// fp32 -> bf16 elementwise convert (hidden), 8 elems/thread
// ---------------------------------------------------------------------------
__global__ __launch_bounds__(256) void convert_kernel(
    const float* __restrict__ in, bf16* __restrict__ out)
{
    const size_t i0 = ((size_t)blockIdx.x * 256 + threadIdx.x) * 8;
    const float4 a = *(const float4*)(in + i0);
    const float4 b = *(const float4*)(in + i0 + 4);
    bf16x8 p;
    p[0] = (bf16)a.x; p[1] = (bf16)a.y; p[2] = (bf16)a.z; p[3] = (bf16)a.w;
    p[4] = (bf16)b.x; p[5] = (bf16)b.y; p[6] = (bf16)b.z; p[7] = (bf16)b.w;
    *(bf16x8*)(out + i0) = p;
}

// ---------------------------------------------------------------------------
// Weight transpose + fp32->bf16: in [K=4096][N] row-major -> out [N][4096].
// ---------------------------------------------------------------------------
__global__ __launch_bounds__(256) void transpose_conv_kernel(
    const float* __restrict__ in, bf16* __restrict__ out, int N)
{
    __shared__ bf16 tile[32 * 68];
    const int n0 = blockIdx.x * 32, k0 = blockIdx.y * 64;
    const int t = threadIdx.x;
    const int nn = t & 31, kk0 = (t >> 5) * 8;
#pragma unroll
    for (int j = 0; j < 8; ++j)
        tile[nn * 68 + kk0 + j] = (bf16)in[(size_t)(k0 + kk0 + j) * N + n0 + nn];
    __syncthreads();
    const int n2 = t >> 3, c = (t & 7) * 8;
    *(bf16x8*)(out + (size_t)(n0 + n2) * 4096 + k0 + c) = *(const bf16x8*)(&tile[n2 * 68 + c]);
}

// ---------------------------------------------------------------------------
// 8-phase 256^2 GEMM (m201-style template): C[4096, NCOLS] = A * B^T (+bias).
// BM=BN=256, BK=64, 512 thr / 8 waves (2Mx4N). Wave owns interleaved tiles:
//   m-tiles {m*2+wr}, n-tiles {n*4+wc}  ->  phase quadrant == LDS half-region.
// LDS 128KiB: [buf][half][kk][128][32] per A/B, st_16x32 swizzle
// (col ^= 16 when row bit3 set), applied on pre-swizzled glds SOURCE and on
// ds_read address (both-sides rule).
// Pipeline: 1 half-tile staged per phase, 3 half-tiles in flight, counted
// vmcnt(6) once per K-tile (phase 4); drains only at the last 2 boundaries.
// Phase: {ds_read quadrant frags; stage; bar; setprio1; 16 MFMA; setprio0; bar}.
// EPI 0: bias + q->[b,s,h,d], k/v scattered ->[b,kv,s,d].  EPI 1: fp32 out.
// ---------------------------------------------------------------------------
#define G256_LDA(dst, bufv, mh)                                                 \
    do {                                                                        \
        _Pragma("unroll")                                                       \
        for (int m_ = 0; m_ < 4; ++m_) {                                        \
            const int rowh_ = (m_ * 2 + wr) * 16 + l15;                         \
            const int colp_ = (quad * 8) ^ (((rowh_ >> 3) & 1) << 4);           \
            const int bse_ = ((bufv) * 2 + (mh)) * 8192 + rowh_ * 32 + colp_;   \
            dst[m_][0] = *(const bf16x8*)&Lds[bse_];                            \
            dst[m_][1] = *(const bf16x8*)&Lds[bse_ + 4096];                     \
        }                                                                       \
    } while (0)

#define G256_LDB(dst, bufv, nh)                                                 \
    do {                                                                        \
        _Pragma("unroll")                                                       \
        for (int n_ = 0; n_ < 2; ++n_) {                                        \
            const int rowh_ = (n_ * 4 + wc) * 16 + l15;                         \
            const int colp_ = (quad * 8) ^ (((rowh_ >> 3) & 1) << 4);           \
            const int bse_ = 32768 + ((bufv) * 2 + (nh)) * 8192 +               \
                             rowh_ * 32 + colp_;                                \
            dst[n_][0] = *(const bf16x8*)&Lds[bse_];                            \
            dst[n_][1] = *(const bf16x8*)&Lds[bse_ + 4096];                     \
        }                                                                       \
    } while (0)

#define G256_QUAD(av, bv, mh, nh)                                               \
    do {                                                                        \
        __builtin_amdgcn_s_setprio(1);                                          \
        _Pragma("unroll")                                                       \
        for (int m_ = 0; m_ < 4; ++m_)                                          \
            _Pragma("unroll")                                                   \
            for (int n_ = 0; n_ < 2; ++n_) {                                    \
                acc[(mh) * 4 + m_][(nh) * 2 + n_] =                             \
                    __builtin_amdgcn_mfma_f32_16x16x32_bf16(                    \
                        av[m_][0], bv[n_][0], acc[(mh) * 4 + m_][(nh) * 2 + n_],\
                        0, 0, 0);                                               \
                acc[(mh) * 4 + m_][(nh) * 2 + n_] =                             \
                    __builtin_amdgcn_mfma_f32_16x16x32_bf16(                    \
                        av[m_][1], bv[n_][1], acc[(mh) * 4 + m_][(nh) * 2 + n_],\
                        0, 0, 0);                                               \
            }                                                                   \
        __builtin_amdgcn_s_setprio(0);                                          \
    } while (0)

template <int EPI>
__global__ __launch_bounds__(512) void gemm256_kernel(
    const bf16* __restrict__ A,
    const bf16* __restrict__ BqT, const bf16* __restrict__ BkT, const bf16* __restrict__ BvT,
    const float* __restrict__ b_q, const float* __restrict__ b_k, const float* __restrict__ b_v,
    bf16* __restrict__ q_out, bf16* __restrict__ kv_k, bf16* __restrict__ kv_v,
    float* __restrict__ f_out, int nwg)
{
    __shared__ bf16 Lds[65536];   // A elems [0,32768), B elems [32768,65536)

    const int tid = threadIdx.x;
    const int wv = tid >> 6, lane = tid & 63;
    const int l15 = lane & 15, quad = lane >> 4;
    const int wr = wv >> 2, wc = wv & 3;

    // XCD-aware bijective swizzle (nwg % 8 == 0)
    const int bid = blockIdx.x;
    const int swz = (bid & 7) * (nwg >> 3) + (bid >> 3);
    const int mt = swz & 15, nt = swz >> 4;
    const int row0 = mt * 256;

    const bf16* BT;
    const float* biasp = nullptr;
    bf16* dstkv = nullptr;
    int sel = 0, bcol0, ocol0 = nt * 256, lcol0 = 0;
    if (EPI == 0) {
        if (nt < 16)      { BT = BqT; bcol0 = nt * 256; biasp = b_q + nt * 256; sel = 0; }
        else if (nt < 20) { BT = BkT; bcol0 = (nt - 16) * 256; biasp = b_k + (nt - 16) * 256;
                            sel = 1; dstkv = kv_k; lcol0 = (nt - 16) * 256; }
        else              { BT = BvT; bcol0 = (nt - 20) * 256; biasp = b_v + (nt - 20) * 256;
                            sel = 2; dstkv = kv_v; lcol0 = (nt - 20) * 256; }
    } else {
        BT = BqT; bcol0 = nt * 256;
    }

    // stage one half-tile (item n): n -> tile T = n>>2, j = n&3,
    // order [A-half0, B-half0, B-half1, A-half1]; target buf = T&1.
    auto stage = [&](int n) {
        if (n >= 256) return;
        const int T = n >> 2, j = n & 3;
        const int buf = T & 1;
        const bool isA = (j == 0 || j == 3);
        const int half = (j == 0) ? 0 : (j == 3) ? 1 : (j - 1);
        const int k0 = T * 64;
        const bf16* g = isA ? (A + (size_t)(row0 + half * 128) * 4096)
                            : (BT + (size_t)(bcol0 + half * 128) * 4096);
        bf16* lb = &Lds[(isA ? 0 : 32768) + (buf * 2 + half) * 8192];
#pragma unroll
        for (int jj = 0; jj < 2; ++jj) {
            const int pc = (wv * 2 + jj) * 64 + lane;      // phys 16B chunk
            const int kk = pc >> 9, rem = pc & 511;
            const int row = rem >> 2, ccp = rem & 3;
            const int ccl = ccp ^ ((row >> 2) & 2);        // inverse swizzle
            glds16(g + (size_t)row * 4096 + k0 + kk * 32 + ccl * 8,
                   lb + (wv * 2 + jj) * 512);
        }
    };

    const f32x4 vzero = {0.f, 0.f, 0.f, 0.f};
    f32x4 acc[8][4];
#pragma unroll
    for (int mi = 0; mi < 8; ++mi)
#pragma unroll
        for (int ni = 0; ni < 4; ++ni) acc[mi][ni] = vzero;

    bf16x8 a[4][2], b0[2][2], b1[2][2];

    // ---- prologue: items 0..6 (tile0 full + tile1 A0,B0,B1) ----
    for (int n = 0; n < 7; ++n) stage(n);
    asm volatile("s_waitcnt vmcnt(6)" ::: "memory");
    __builtin_amdgcn_s_barrier();

    for (int t = 0; t < 64; ++t) {
        const int buf = t & 1;
        const int nb = 4 * t;
        // ---- phase 1: quadrant (mh0,nh0) ----
        G256_LDA(a, buf, 0);
        G256_LDB(b0, buf, 0);
        stage(nb + 7);
        __builtin_amdgcn_s_barrier();
        G256_QUAD(a, b0, 0, 0);
        __builtin_amdgcn_s_barrier();
        // ---- phase 2: (mh0,nh1) ----
        G256_LDB(b1, buf, 1);
        stage(nb + 8);
        __builtin_amdgcn_s_barrier();
        G256_QUAD(a, b1, 0, 1);
        __builtin_amdgcn_s_barrier();
        // ---- phase 3: (mh1,nh0) ----
        G256_LDA(a, buf, 1);
        stage(nb + 9);
        __builtin_amdgcn_s_barrier();
        G256_QUAD(a, b0, 1, 0);
        __builtin_amdgcn_s_barrier();
        // ---- phase 4: (mh1,nh1) + tile-boundary counted wait ----
        stage(nb + 10);
        __builtin_amdgcn_s_barrier();
        G256_QUAD(a, b1, 1, 1);
        if (t < 62)       asm volatile("s_waitcnt vmcnt(6)" ::: "memory");
        else if (t == 62) asm volatile("s_waitcnt vmcnt(0)" ::: "memory");
        __builtin_amdgcn_s_barrier();
    }

    // ---- epilogue ----
#pragma unroll
    for (int mi = 0; mi < 8; ++mi) {
        const int mtile = (mi >> 2) * 8 + (mi & 3) * 2 + wr;
#pragma unroll
        for (int ni = 0; ni < 4; ++ni) {
            const int ntile = ni * 4 + wc;
            const int gcl = ntile * 16 + l15;
#pragma unroll
            for (int i = 0; i < 4; ++i) {
                const int gr = row0 + mtile * 16 + quad * 4 + i;
                float vv = acc[mi][ni][i];
                if (EPI == 1) {
                    f_out[(size_t)gr * 4096 + ocol0 + gcl] = vv;
                } else {
                    vv += biasp[gcl];
                    if (sel == 0) {
                        q_out[(size_t)gr * 4096 + ocol0 + gcl] = (bf16)vv;
                    } else {
                        const int lc = lcol0 + gcl;
                        dstkv[(size_t)((gr >> 11) * 8 + (lc >> 7)) * 262144 +
                              (size_t)(gr & 2047) * 128 + (lc & 127)] = (bf16)vv;
                    }
                }
            }
        }
    }
}

// ---------------------------------------------------------------------------
// Fallback GEMM (m97 128^2) — used only when workspace too small for hid_b.
// ---------------------------------------------------------------------------
template <int EPI, int AF32>
__global__ __launch_bounds__(256) void gemm_kernel(
    const float* __restrict__ A_f32, const bf16* __restrict__ A_bf16,
    const bf16* __restrict__ BqT, const bf16* __restrict__ BkT, const bf16* __restrict__ BvT,
    const float* __restrict__ b_q, const float* __restrict__ b_k, const float* __restrict__ b_v,
    bf16* __restrict__ q_out, bf16* __restrict__ kv_k, bf16* __restrict__ kv_v,
    float* __restrict__ f_out)
{
    constexpr int LDA = AF32 ? 34 : 32;
    __shared__ bf16 As[128 * LDA];
    __shared__ bf16 Bs[128 * 32];

    const int nt = blockIdx.x, mt = blockIdx.y;
    const int tid = threadIdx.x;
    const int wave = tid >> 6, lane = tid & 63;
    const int l15 = lane & 15, quad = lane >> 4;
    const int wm = (wave >> 1) * 64, wn = (wave & 1) * 64;

    const bf16* BT;
    const float* bias = nullptr;
    int sel = 0, ncol0;
    if (EPI == 0) {
        if (nt < 32)      { BT = BqT; bias = b_q; sel = 0; ncol0 = nt * 128; }
        else if (nt < 40) { BT = BkT; bias = b_k; sel = 1; ncol0 = (nt - 32) * 128; }
        else              { BT = BvT; bias = b_v; sel = 2; ncol0 = (nt - 40) * 128; }
    } else {
        BT = BqT; ncol0 = nt * 128;
    }
    const int row0 = mt * 128;

    const f32x4 vzero = {0.f, 0.f, 0.f, 0.f};
    f32x4 acc[4][4];
#pragma unroll
    for (int mi = 0; mi < 4; ++mi)
#pragma unroll
        for (int ni = 0; ni < 4; ++ni) acc[mi][ni] = vzero;

    const int a_row = tid >> 1, a_seg = (tid & 1) * 16;
    const int g_row = lane >> 2, g_seg = (lane & 3) * 8;

    for (int k0 = 0; k0 < 4096; k0 += 32) {
        if (AF32) {
            const float4* src = (const float4*)(A_f32 + (size_t)(row0 + a_row) * 4096 + k0 + a_seg);
            float4 f0 = src[0], f1 = src[1], f2 = src[2], f3 = src[3];
            bf16x8 p0, p1;
            p0[0] = (bf16)f0.x; p0[1] = (bf16)f0.y; p0[2] = (bf16)f0.z; p0[3] = (bf16)f0.w;
            p0[4] = (bf16)f1.x; p0[5] = (bf16)f1.y; p0[6] = (bf16)f1.z; p0[7] = (bf16)f1.w;
            p1[0] = (bf16)f2.x; p1[1] = (bf16)f2.y; p1[2] = (bf16)f2.z; p1[3] = (bf16)f2.w;
            p1[4] = (bf16)f3.x; p1[5] = (bf16)f3.y; p1[6] = (bf16)f3.z; p1[7] = (bf16)f3.w;
            *(bf16x8*)(&As[a_row * LDA + a_seg]) = p0;
            *(bf16x8*)(&As[a_row * LDA + a_seg + 8]) = p1;
        } else {
#pragma unroll
            for (int c = 0; c < 2; ++c)
                glds16(A_bf16 + (size_t)(row0 + wave * 32 + c * 16 + g_row) * 4096 + k0 + g_seg,
                       &As[(wave * 32 + c * 16) * 32]);
        }
#pragma unroll
        for (int c = 0; c < 2; ++c)
            glds16(BT + (size_t)(ncol0 + wave * 32 + c * 16 + g_row) * 4096 + k0 + g_seg,
                   &Bs[(wave * 32 + c * 16) * 32]);
        __syncthreads();

        bf16x8 af[4], bfv[4];
#pragma unroll
        for (int mi = 0; mi < 4; ++mi)
            af[mi] = *(const bf16x8*)(&As[(wm + mi * 16 + l15) * LDA + quad * 8]);
#pragma unroll
        for (int ni = 0; ni < 4; ++ni)
            bfv[ni] = *(const bf16x8*)(&Bs[(wn + ni * 16 + l15) * 32 + quad * 8]);
#pragma unroll
        for (int mi = 0; mi < 4; ++mi)
#pragma unroll
            for (int ni = 0; ni < 4; ++ni)
                acc[mi][ni] = __builtin_amdgcn_mfma_f32_16x16x32_bf16(af[mi], bfv[ni], acc[mi][ni], 0, 0, 0);
        __syncthreads();
    }

#pragma unroll
    for (int mi = 0; mi < 4; ++mi)
#pragma unroll
        for (int ni = 0; ni < 4; ++ni)
#pragma unroll
            for (int i = 0; i < 4; ++i) {
                const int gr = row0 + wm + mi * 16 + quad * 4 + i;
                const int gc = ncol0 + wn + ni * 16 + l15;
                float vv = acc[mi][ni][i];
                if (EPI == 1) {
                    f_out[(size_t)gr * 4096 + gc] = vv;
                } else {
                    vv += bias[gc];
                    if (sel == 0) {
                        q_out[(size_t)gr * 4096 + gc] = (bf16)vv;
                    } else {
                        bf16* dst = (sel == 1) ? kv_k : kv_v;
                        dst[(size_t)((gr >> 11) * 8 + (gc >> 7)) * 262144 +
                            (size_t)(gr & 2047) * 128 + (gc & 127)] = (bf16)vv;
                    }
                }
            }
}

// ---------------------------------------------------------------------------
// In-place RoPE. Q [b,s,h,128] (scale folded); K [b,kv,s,128].
// ---------------------------------------------------------------------------
__global__ __launch_bounds__(256) void rope_q_kernel(
    bf16* __restrict__ q, const int* __restrict__ pos_ids)
{
    const int idx = blockIdx.x * 256 + threadIdx.x;
    const int d = idx & 63, h = (idx >> 6) & 31, tok = idx >> 11;
    const float posv = (float)pos_ids[tok];
    const float fr = exp2f((float)d * (-19.931568569324174f / 64.f));
    float sn, cs;
    sincosf(posv * fr, &sn, &cs);
    bf16* xp = q + (size_t)tok * 4096 + h * 128 + d;
    const float x1 = (float)xp[0], x2 = (float)xp[64];
    const float scale = 0.08838834764831845f;
    xp[0]  = (bf16)((x1 * cs - x2 * sn) * scale);
    xp[64] = (bf16)((x1 * sn + x2 * cs) * scale);
}

__global__ __launch_bounds__(256) void rope_k_kernel(
    bf16* __restrict__ k, const int* __restrict__ pos_ids)
{
    const int idx = blockIdx.x * 256 + threadIdx.x;
    const int d = idx & 63, s = (idx >> 6) & 2047, bk = idx >> 17;
    const int b = bk >> 3;
    const float posv = (float)pos_ids[b * 2048 + s];
    const float fr = exp2f((float)d * (-19.931568569324174f / 64.f));
    float sn, cs;
    sincosf(posv * fr, &sn, &cs);
    bf16* xp = k + ((size_t)bk * 2048 + s) * 128 + d;
    const float x1 = (float)xp[0], x2 = (float)xp[64];
    xp[0]  = (bf16)(x1 * cs - x2 * sn);
    xp[64] = (bf16)(x1 * sn + x2 * cs);
}

// ---------------------------------------------------------------------------
// Flash attention, causal, GQA (R3 version: swapped-QK^T in-register softmax,
// defer-max, balanced q-tile pairs).
// ---------------------------------------------------------------------------
__global__ __launch_bounds__(256) void attn_kernel(
    const bf16* __restrict__ q, const bf16* __restrict__ k,
    const bf16* __restrict__ v, bf16* __restrict__ o)
{
    __shared__ bf16 Ksl[64 * 136];      // [kv][d]
    __shared__ bf16 Vsl[128 * 72];      // [d][kv]
    __shared__ bf16 Psl[4 * 16 * 68];   // per-wave [qrow][kv]

    const int pair = blockIdx.x & 7;
    const int h  = (blockIdx.x >> 3) & 31;
    const int b  = blockIdx.x >> 8;
    const int kvh = h >> 2;
    const int tid = threadIdx.x;
    const int wave = tid >> 6, lane = tid & 63;
    const int l15 = lane & 15, quad = lane >> 4;

    const bf16* kbase = k + (size_t)(b * 8 + kvh) * 2048 * 128;
    const bf16* vbase = v + (size_t)(b * 8 + kvh) * 2048 * 128;

    const int kr = tid >> 2, ksg = (tid & 3) * 32;
    const f32x4 vzero = {0.f, 0.f, 0.f, 0.f};

#pragma unroll 1
    for (int phase = 0; phase < 2; ++phase) {
        const int qt = phase ? (15 - pair) : pair;
        const int qbase = qt * 128 + wave * 32;

        bf16x8 qf[2][4];
#pragma unroll
        for (int mi = 0; mi < 2; ++mi) {
            const bf16* qrow = q + ((size_t)(b * 2048 + qbase + mi * 16 + l15) * 32 + h) * 128;
#pragma unroll
            for (int kb = 0; kb < 4; ++kb)
                qf[mi][kb] = *(const bf16x8*)(qrow + kb * 32 + quad * 8);
        }

        f32x4 acc_o[2][8];
#pragma unroll
        for (int mi = 0; mi < 2; ++mi)
#pragma unroll
            for (int i = 0; i < 8; ++i) acc_o[mi][i] = vzero;
        float m_i[2] = {-INFINITY, -INFINITY};
        float l_i[2] = {0.f, 0.f};

        const int nT = 2 * qt + 2;
        for (int t = 0; t < nT; ++t) {
            const int kv0 = t * 64;
            {
                const bf16x8* ks = (const bf16x8*)(kbase + (size_t)(kv0 + kr) * 128 + ksg);
                bf16x8* kd = (bf16x8*)(&Ksl[kr * 136 + ksg]);
                kd[0] = ks[0]; kd[1] = ks[1]; kd[2] = ks[2]; kd[3] = ks[3];
            }
            {
                const bf16x8* vs = (const bf16x8*)(vbase + (size_t)(kv0 + lane) * 128 + wave * 32);
                bf16x8 w0 = vs[0], w1 = vs[1], w2 = vs[2], w3 = vs[3];
#pragma unroll
                for (int i = 0; i < 8; ++i) {
                    Vsl[(wave * 32 + i)      * 72 + lane] = w0[i];
                    Vsl[(wave * 32 + 8 + i)  * 72 + lane] = w1[i];
                    Vsl[(wave * 32 + 16 + i) * 72 + lane] = w2[i];
                    Vsl[(wave * 32 + 24 + i) * 72 + lane] = w3[i];
                }
            }
            __syncthreads();

            if (kv0 <= qbase + 31) {
                f32x4 sacc[2][4];
#pragma unroll
                for (int mi = 0; mi < 2; ++mi)
#pragma unroll
                    for (int nt = 0; nt < 4; ++nt) sacc[mi][nt] = vzero;
                __builtin_amdgcn_s_setprio(1);
#pragma unroll
                for (int nt = 0; nt < 4; ++nt)
#pragma unroll
                    for (int kb = 0; kb < 4; ++kb) {
                        const bf16x8 kf = *(const bf16x8*)(&Ksl[(nt * 16 + l15) * 136 + kb * 32 + quad * 8]);
                        sacc[0][nt] = __builtin_amdgcn_mfma_f32_16x16x32_bf16(kf, qf[0][kb], sacc[0][nt], 0, 0, 0);
                        sacc[1][nt] = __builtin_amdgcn_mfma_f32_16x16x32_bf16(kf, qf[1][kb], sacc[1][nt], 0, 0, 0);
                    }
                __builtin_amdgcn_s_setprio(0);

                bf16x8 pf[2][2];
#pragma unroll
                for (int mi = 0; mi < 2; ++mi) {
                    const int rb = qbase + mi * 16;
                    if (kv0 + 63 > rb) {
#pragma unroll
                        for (int nt = 0; nt < 4; ++nt) {
                            const int kvr = kv0 + nt * 16 + quad * 4;
#pragma unroll
                            for (int i = 0; i < 4; ++i)
                                if (kvr + i > rb + l15) sacc[mi][nt][i] = -INFINITY;
                        }
                    }
                    float tm;
                    {
                        f32x4 m4;
#pragma unroll
                        for (int i = 0; i < 4; ++i)
                            m4[i] = fmaxf(fmaxf(sacc[mi][0][i], sacc[mi][1][i]),
                                          fmaxf(sacc[mi][2][i], sacc[mi][3][i]));
                        tm = fmaxf(fmaxf(m4[0], m4[1]), fmaxf(m4[2], m4[3]));
                        tm = fmaxf(tm, __shfl_xor(tm, 16, 64));
                        tm = fmaxf(tm, __shfl_xor(tm, 32, 64));
                    }
                    if (!__all(tm - m_i[mi] <= 8.f)) {
                        const float mnew = fmaxf(m_i[mi], tm);
                        const float alpha = __expf(m_i[mi] - mnew);
                        m_i[mi] = mnew;
                        l_i[mi] *= alpha;
                        float aw[4];
#pragma unroll
                        for (int i = 0; i < 4; ++i)
                            aw[i] = __shfl(alpha, quad * 4 + i, 16);
#pragma unroll
                        for (int dn = 0; dn < 8; ++dn)
#pragma unroll
                            for (int i = 0; i < 4; ++i) acc_o[mi][dn][i] *= aw[i];
                    }
                    float p[4][4];
                    float rs = 0.f;
#pragma unroll
                    for (int nt = 0; nt < 4; ++nt)
#pragma unroll
                        for (int i = 0; i < 4; ++i) {
                            p[nt][i] = __expf(sacc[mi][nt][i] - m_i[mi]);
                            rs += p[nt][i];
                        }
                    rs += __shfl_xor(rs, 16, 64);
                    rs += __shfl_xor(rs, 32, 64);
                    l_i[mi] += rs;
#pragma unroll
                    for (int nt = 0; nt < 4; ++nt) {
                        uint2 w;
                        w.x = cvt_pk_bf16(p[nt][0], p[nt][1]);
                        w.y = cvt_pk_bf16(p[nt][2], p[nt][3]);
                        *(uint2*)(&Psl[wave * 1088 + l15 * 68 + nt * 16 + quad * 4]) = w;
                    }
#pragma unroll
                    for (int k2 = 0; k2 < 2; ++k2)
                        pf[mi][k2] = *(const bf16x8*)(&Psl[wave * 1088 + l15 * 68 + k2 * 32 + quad * 8]);
                }

                __builtin_amdgcn_s_setprio(1);
#pragma unroll
                for (int dn = 0; dn < 8; ++dn)
#pragma unroll
                    for (int k2 = 0; k2 < 2; ++k2) {
                        const bf16x8 vf = *(const bf16x8*)(&Vsl[(dn * 16 + l15) * 72 + k2 * 32 + quad * 8]);
                        acc_o[0][dn] = __builtin_amdgcn_mfma_f32_16x16x32_bf16(pf[0][k2], vf, acc_o[0][dn], 0, 0, 0);
                        acc_o[1][dn] = __builtin_amdgcn_mfma_f32_16x16x32_bf16(pf[1][k2], vf, acc_o[1][dn], 0, 0, 0);
                    }
                __builtin_amdgcn_s_setprio(0);
            }
            __syncthreads();
        }

#pragma unroll
        for (int mi = 0; mi < 2; ++mi) {
            const float inv = 1.f / l_i[mi];
            float invw[4];
#pragma unroll
            for (int i = 0; i < 4; ++i)
                invw[i] = __shfl(inv, quad * 4 + i, 16);
#pragma unroll
            for (int dn = 0; dn < 8; ++dn)
#pragma unroll
                for (int i = 0; i < 4; ++i) {
                    const int s = qbase + mi * 16 + quad * 4 + i;
                    o[(((size_t)b * 2048 + s) * 32 + h) * 128 + dn * 16 + l15] =
                        (bf16)(acc_o[mi][dn][i] * invw[i]);
                }
        }
    }
}

// ---------------------------------------------------------------------------
extern "C" void kernel_launch(void* const* d_in, const int* in_sizes, int n_in,
                              void* d_out, int out_size, void* d_ws, size_t ws_size,
                              hipStream_t stream)
{
    (void)in_sizes; (void)n_in; (void)out_size;
    const float* hidden = (const float*)d_in[0];
    const int*   pos    = (const int*)d_in[1];
    const float* wq     = (const float*)d_in[2];
    const float* bq_    = (const float*)d_in[3];
    const float* wk     = (const float*)d_in[4];
    const float* bk_    = (const float*)d_in[5];
    const float* wv     = (const float*)d_in[6];
    const float* bv_    = (const float*)d_in[7];
    const float* wo     = (const float*)d_in[8];
    float* out = (float*)d_out;

    char* ws = (char*)d_ws;
    bf16* wqT   = (bf16*)(ws);                 // 33.5 MB -> attn_o after QKV
    bf16* wkT   = (bf16*)(ws + 33554432);      //  8.4 MB
    bf16* wvT   = (bf16*)(ws + 41943040);      //  8.4 MB
    bf16* q_pre = (bf16*)(ws + 50331648);      // 33.5 MB -> woT after attn
    bf16* k_t   = (bf16*)(ws + 83886080);      //  8.4 MB [b,kv,s,d]
    bf16* v_t   = (bf16*)(ws + 92274688);      //  8.4 MB [b,kv,s,d]
    bf16* hid_b = (bf16*)(ws + 100663296);     // 33.5 MB (if ws allows)
    bf16* attn_o = wqT;
    bf16* woT    = q_pre;
    const bool have_hid = (ws_size >= 134217728);

    // 1) weight transposes (fp32 [K][N] -> bf16 [N][K])
    transpose_conv_kernel<<<dim3(128, 64), 256, 0, stream>>>(wq, wqT, 4096);
    transpose_conv_kernel<<<dim3(32, 64), 256, 0, stream>>>(wk, wkT, 1024);
    transpose_conv_kernel<<<dim3(32, 64), 256, 0, stream>>>(wv, wvT, 1024);

    // 2) QKV projection; K/V written directly to [b,kv,s,d]
    if (have_hid) {
        convert_kernel<<<8192, 256, 0, stream>>>(hidden, hid_b);
        gemm256_kernel<0><<<384, 512, 0, stream>>>(
            hid_b, wqT, wkT, wvT, bq_, bk_, bv_, q_pre, k_t, v_t, nullptr, 384);
    } else {
        gemm_kernel<0, 1><<<dim3(48, 32), 256, 0, stream>>>(
            hidden, nullptr, wqT, wkT, wvT, bq_, bk_, bv_, q_pre, k_t, v_t, nullptr);
    }

    // 3) in-place RoPE (Q gets 1/sqrt(128) folded)
    rope_q_kernel<<<32768, 256, 0, stream>>>(q_pre, pos);
    rope_k_kernel<<<8192, 256, 0, stream>>>(k_t, pos);

    // 4) causal GQA flash attention, balanced q-tile pairs -> attn_o [b,s,h,d]
    attn_kernel<<<512, 256, 0, stream>>>(q_pre, k_t, v_t, attn_o);

    // 5) transpose wo into q_pre region (q dead after attn)
    transpose_conv_kernel<<<dim3(128, 64), 256, 0, stream>>>(wo, woT, 4096);

    // 6) output projection -> d_out (fp32)
    if (have_hid) {
        gemm256_kernel<1><<<256, 512, 0, stream>>>(
            attn_o, woT, nullptr, nullptr, nullptr, nullptr, nullptr,
            nullptr, nullptr, nullptr, out, 256);
    } else {
        gemm_kernel<1, 0><<<dim3(32, 32), 256, 0, stream>>>(
            nullptr, attn_o, woT, nullptr, nullptr, nullptr, nullptr, nullptr,
            nullptr, nullptr, nullptr, out);
    }
}

// Round 5
// 789.438 us; speedup vs baseline: 1.2080x; 1.0093x over previous
//
#include <hip/hip_runtime.h>
#include <hip/hip_bf16.h>
#include <math.h>

// Problem: B=2, S=2048, D=4096, H=32, KV=8, HD=128, N_REP=4, theta=1e6
// Output fp32 (2,2048,4096).

typedef __bf16 bf16;
typedef __attribute__((ext_vector_type(8))) __bf16 bf16x8;
typedef __attribute__((ext_vector_type(4))) float f32x4;

// async global->LDS, 16 B per lane; LDS dest = wave-uniform base + lane*16
__device__ __forceinline__ void glds16(const void* g, void* l) {
    __builtin_amdgcn_global_load_lds(
        (const __attribute__((address_space(1))) void*)g,
        (__attribute__((address_space(3))) void*)l, 16, 0, 0);
}

// v_cvt_pk_bf16_f32: dst.lo = bf16(lo), dst.hi = bf16(hi)  (no builtin; T12)
__device__ __forceinline__ unsigned cvt_pk_bf16(float lo, float hi) {
    unsigned r;
    asm("v_cvt_pk_bf16_f32 %0, %1, %2" : "=v"(r) : "v"(lo), "v"(hi));
    return r;
}

// ---------------------------------------------------------------------------
// fp32 -> bf16 elementwise convert (hidden), 8 elems/thread
// ---------------------------------------------------------------------------
__global__ __launch_bounds__(256) void convert_kernel(
    const float* __restrict__ in, bf16* __restrict__ out)
{
    const size_t i0 = ((size_t)blockIdx.x * 256 + threadIdx.x) * 8;
    const float4 a = *(const float4*)(in + i0);
    const float4 b = *(const float4*)(in + i0 + 4);
    bf16x8 p;
    p[0] = (bf16)a.x; p[1] = (bf16)a.y; p[2] = (bf16)a.z; p[3] = (bf16)a.w;
    p[4] = (bf16)b.x; p[5] = (bf16)b.y; p[6] = (bf16)b.z; p[7] = (bf16)b.w;
    *(bf16x8*)(out + i0) = p;
}

// ---------------------------------------------------------------------------
// Weight transpose + fp32->bf16: in [K=4096][N] row-major -> out [N][4096].
// ---------------------------------------------------------------------------
__global__ __launch_bounds__(256) void transpose_conv_kernel(
    const float* __restrict__ in, bf16* __restrict__ out, int N)
{
    __shared__ bf16 tile[32 * 68];
    const int n0 = blockIdx.x * 32, k0 = blockIdx.y * 64;
    const int t = threadIdx.x;
    const int nn = t & 31, kk0 = (t >> 5) * 8;
#pragma unroll
    for (int j = 0; j < 8; ++j)
        tile[nn * 68 + kk0 + j] = (bf16)in[(size_t)(k0 + kk0 + j) * N + n0 + nn];
    __syncthreads();
    const int n2 = t >> 3, c = (t & 7) * 8;
    *(bf16x8*)(out + (size_t)(n0 + n2) * 4096 + k0 + c) = *(const bf16x8*)(&tile[n2 * 68 + c]);
}

// ---------------------------------------------------------------------------
// QKV GEMM, 128x256 tile, BK=64, 512 thr / 8 waves (2Mx4N), 2 phases/K-tile.
// Grid 32x24 = 768 blocks = EXACTLY 3 rounds of 256 CUs (no quantization).
// LDS 96 KiB: A [buf][128][64] @0, B [buf][half][128][64] @16384 (elems).
// XOR swizzle for 128B rows: col ^= (row&7)*8 (elems), pre-swizzled glds src.
// Pipeline (6 stage-items/tile of 8KB each):
//   phase A: 12 ds_read + stage(t+1 B1 x2) + bar + 16 MFMA + bar
//   phase B:  4 ds_read + stage(t+2 A,B0 x4) + bar + 16 MFMA + vmcnt(4) + bar
// Safety: t+2 items land in buf[t&1] only in regions whose tile-t reads
// completed in phase A; boundary vmcnt(4) guarantees tile t+1 fully landed.
// Epilogue: bias + q->[b,s,h,d], k/v scattered ->[b,kv,s,d].
// ---------------------------------------------------------------------------
#define QKV_LDA(dst, bufv)                                                    \
  { _Pragma("unroll") for (int m_ = 0; m_ < 4; ++m_) {                        \
      const int row_ = (wr * 4 + m_) * 16 + l15;                              \
      const int bse_ = (bufv) * 8192 + row_ * 64;                             \
      dst[m_][0] = *(const bf16x8*)&Lds[bse_ + ((quad * 8) ^ xk)];            \
      dst[m_][1] = *(const bf16x8*)&Lds[bse_ + ((32 + quad * 8) ^ xk)];       \
    } }

#define QKV_LDB(dst, bufv, nh)                                                \
  { _Pragma("unroll") for (int n_ = 0; n_ < 2; ++n_) {                        \
      const int rowh_ = (n_ * 4 + wc) * 16 + l15;                             \
      const int bse_ = 16384 + ((bufv) * 2 + (nh)) * 8192 + rowh_ * 64;       \
      dst[n_][0] = *(const bf16x8*)&Lds[bse_ + ((quad * 8) ^ xk)];            \
      dst[n_][1] = *(const bf16x8*)&Lds[bse_ + ((32 + quad * 8) ^ xk)];       \
    } }

#define QKV_QUAD(av, bv, nh)                                                  \
  { __builtin_amdgcn_s_setprio(1);                                           \
    _Pragma("unroll") for (int m_ = 0; m_ < 4; ++m_)                          \
      _Pragma("unroll") for (int n_ = 0; n_ < 2; ++n_) {                      \
        acc[m_][(nh) * 2 + n_] = __builtin_amdgcn_mfma_f32_16x16x32_bf16(     \
            av[m_][0], bv[n_][0], acc[m_][(nh) * 2 + n_], 0, 0, 0);           \
        acc[m_][(nh) * 2 + n_] = __builtin_amdgcn_mfma_f32_16x16x32_bf16(     \
            av[m_][1], bv[n_][1], acc[m_][(nh) * 2 + n_], 0, 0, 0);           \
      }                                                                       \
    __builtin_amdgcn_s_setprio(0); }

__global__ __launch_bounds__(512) void gemm_qkv_kernel(
    const bf16* __restrict__ A,
    const bf16* __restrict__ BqT, const bf16* __restrict__ BkT, const bf16* __restrict__ BvT,
    const float* __restrict__ b_q, const float* __restrict__ b_k, const float* __restrict__ b_v,
    bf16* __restrict__ q_out, bf16* __restrict__ kv_k, bf16* __restrict__ kv_v)
{
    __shared__ bf16 Lds[49152];   // 96 KiB

    const int tid = threadIdx.x;
    const int wv = tid >> 6, lane = tid & 63;
    const int l15 = lane & 15, quad = lane >> 4;
    const int wr = wv >> 2, wc = wv & 3;
    const int xk = (l15 & 7) * 8;

    // XCD-aware swizzle, nwg=768 (%8==0); consecutive swz share mt (A in L2)
    const int bid = blockIdx.x;
    const int swz = (bid & 7) * 96 + (bid >> 3);
    const int mt = swz / 24, nt = swz % 24;
    const int row0 = mt * 128;

    const bf16* BT;
    const float* biasp;
    bf16* dstkv = nullptr;
    int sel, bcol0, lcol0 = 0, qcol0 = 0;
    if (nt < 16)      { BT = BqT; bcol0 = nt * 256; biasp = b_q + bcol0; sel = 0; qcol0 = bcol0; }
    else if (nt < 20) { BT = BkT; bcol0 = (nt - 16) * 256; biasp = b_k + bcol0; sel = 1;
                        dstkv = kv_k; lcol0 = bcol0; }
    else              { BT = BvT; bcol0 = (nt - 20) * 256; biasp = b_v + bcol0; sel = 2;
                        dstkv = kv_v; lcol0 = bcol0; }

    // stage item (T, j): j 0,1 = A rows j*64; j 2..5 = B half=(j-2)>>1, sub=(j-2)&1.
    // 8KB/item: each wave 1 glds16 (1KB). Pre-swizzled global source.
    auto stage = [&](int T, int j) {
        if (T >= 64) return;
        const int buf = T & 1;
        const int k0 = T * 64;
        const int r = wv * 8 + (lane >> 3);            // item-local row 0..63
        const int gcol = k0 + (((lane & 7) * 8) ^ ((r & 7) * 8));
        const bf16* g;
        int ldsbase;
        if (j < 2) {
            g = A + (size_t)(row0 + j * 64 + r) * 4096 + gcol;
            ldsbase = buf * 8192 + j * 4096;
        } else {
            const int half = (j - 2) >> 1, sub = (j - 2) & 1;
            g = BT + (size_t)(bcol0 + half * 128 + sub * 64 + r) * 4096 + gcol;
            ldsbase = 16384 + (buf * 2 + half) * 8192 + sub * 4096;
        }
        glds16(g, &Lds[ldsbase + wv * 512]);
    };

    const f32x4 vzero = {0.f, 0.f, 0.f, 0.f};
    f32x4 acc[4][4];
#pragma unroll
    for (int m_ = 0; m_ < 4; ++m_)
#pragma unroll
        for (int n_ = 0; n_ < 4; ++n_) acc[m_][n_] = vzero;

    bf16x8 a[4][2], b0[2][2], b1[2][2];

    // ---- prologue: tile0 all + tile1 A,B0 ----
    for (int j = 0; j < 6; ++j) stage(0, j);
    for (int j = 0; j < 4; ++j) stage(1, j);
    asm volatile("s_waitcnt vmcnt(4)" ::: "memory");
    __builtin_amdgcn_s_barrier();

    for (int t = 0; t < 64; ++t) {
        const int buf = t & 1;
        // ---- phase A: all A + B-half0 ----
        QKV_LDA(a, buf);
        QKV_LDB(b0, buf, 0);
        stage(t + 1, 4); stage(t + 1, 5);
        __builtin_amdgcn_s_barrier();
        QKV_QUAD(a, b0, 0);
        __builtin_amdgcn_s_barrier();
        // ---- phase B: B-half1 ----
        QKV_LDB(b1, buf, 1);
        stage(t + 2, 0); stage(t + 2, 1); stage(t + 2, 2); stage(t + 2, 3);
        __builtin_amdgcn_s_barrier();
        QKV_QUAD(a, b1, 1);
        if (t < 62)       asm volatile("s_waitcnt vmcnt(4)" ::: "memory");
        else if (t == 62) asm volatile("s_waitcnt vmcnt(0)" ::: "memory");
        __builtin_amdgcn_s_barrier();
    }

    // ---- epilogue ----
#pragma unroll
    for (int m_ = 0; m_ < 4; ++m_) {
#pragma unroll
        for (int n_ = 0; n_ < 4; ++n_) {
            const int gcl = (n_ * 4 + wc) * 16 + l15;
#pragma unroll
            for (int i = 0; i < 4; ++i) {
                const int gr = row0 + (wr * 4 + m_) * 16 + quad * 4 + i;
                float vv = acc[m_][n_][i] + biasp[gcl];
                if (sel == 0) {
                    q_out[(size_t)gr * 4096 + qcol0 + gcl] = (bf16)vv;
                } else {
                    const int lc = lcol0 + gcl;
                    dstkv[(size_t)((gr >> 11) * 8 + (lc >> 7)) * 262144 +
                          (size_t)(gr & 2047) * 128 + (lc & 127)] = (bf16)vv;
                }
            }
        }
    }
}

// ---------------------------------------------------------------------------
// 8-phase 256^2 GEMM (R4, verified) — used for the WO projection (256 blocks
// = exactly 1 round). See R4 notes; EPI 1: fp32 out.
// ---------------------------------------------------------------------------
#define G256_LDA(dst, bufv, mh)                                                 \
    do {                                                                        \
        _Pragma("unroll")                                                       \
        for (int m_ = 0; m_ < 4; ++m_) {                                        \
            const int rowh_ = (m_ * 2 + wr) * 16 + l15;                         \
            const int colp_ = (quad * 8) ^ (((rowh_ >> 3) & 1) << 4);           \
            const int bse_ = ((bufv) * 2 + (mh)) * 8192 + rowh_ * 32 + colp_;   \
            dst[m_][0] = *(const bf16x8*)&Lds[bse_];                            \
            dst[m_][1] = *(const bf16x8*)&Lds[bse_ + 4096];                     \
        }                                                                       \
    } while (0)

#define G256_LDB(dst, bufv, nh)                                                 \
    do {                                                                        \
        _Pragma("unroll")                                                       \
        for (int n_ = 0; n_ < 2; ++n_) {                                        \
            const int rowh_ = (n_ * 4 + wc) * 16 + l15;                         \
            const int colp_ = (quad * 8) ^ (((rowh_ >> 3) & 1) << 4);           \
            const int bse_ = 32768 + ((bufv) * 2 + (nh)) * 8192 +               \
                             rowh_ * 32 + colp_;                                \
            dst[n_][0] = *(const bf16x8*)&Lds[bse_];                            \
            dst[n_][1] = *(const bf16x8*)&Lds[bse_ + 4096];                     \
        }                                                                       \
    } while (0)

#define G256_QUAD(av, bv, mh, nh)                                               \
    do {                                                                        \
        __builtin_amdgcn_s_setprio(1);                                          \
        _Pragma("unroll")                                                       \
        for (int m_ = 0; m_ < 4; ++m_)                                          \
            _Pragma("unroll")                                                   \
            for (int n_ = 0; n_ < 2; ++n_) {                                    \
                acc[(mh) * 4 + m_][(nh) * 2 + n_] =                             \
                    __builtin_amdgcn_mfma_f32_16x16x32_bf16(                    \
                        av[m_][0], bv[n_][0], acc[(mh) * 4 + m_][(nh) * 2 + n_],\
                        0, 0, 0);                                               \
                acc[(mh) * 4 + m_][(nh) * 2 + n_] =                             \
                    __builtin_amdgcn_mfma_f32_16x16x32_bf16(                    \
                        av[m_][1], bv[n_][1], acc[(mh) * 4 + m_][(nh) * 2 + n_],\
                        0, 0, 0);                                               \
            }                                                                   \
        __builtin_amdgcn_s_setprio(0);                                          \
    } while (0)

template <int EPI>
__global__ __launch_bounds__(512) void gemm256_kernel(
    const bf16* __restrict__ A,
    const bf16* __restrict__ BqT, const bf16* __restrict__ BkT, const bf16* __restrict__ BvT,
    const float* __restrict__ b_q, const float* __restrict__ b_k, const float* __restrict__ b_v,
    bf16* __restrict__ q_out, bf16* __restrict__ kv_k, bf16* __restrict__ kv_v,
    float* __restrict__ f_out, int nwg)
{
    __shared__ bf16 Lds[65536];

    const int tid = threadIdx.x;
    const int wv = tid >> 6, lane = tid & 63;
    const int l15 = lane & 15, quad = lane >> 4;
    const int wr = wv >> 2, wc = wv & 3;

    const int bid = blockIdx.x;
    const int swz = (bid & 7) * (nwg >> 3) + (bid >> 3);
    const int mt = swz & 15, nt = swz >> 4;
    const int row0 = mt * 256;

    const bf16* BT;
    const float* biasp = nullptr;
    bf16* dstkv = nullptr;
    int sel = 0, bcol0, ocol0 = nt * 256, lcol0 = 0;
    if (EPI == 0) {
        if (nt < 16)      { BT = BqT; bcol0 = nt * 256; biasp = b_q + nt * 256; sel = 0; }
        else if (nt < 20) { BT = BkT; bcol0 = (nt - 16) * 256; biasp = b_k + (nt - 16) * 256;
                            sel = 1; dstkv = kv_k; lcol0 = (nt - 16) * 256; }
        else              { BT = BvT; bcol0 = (nt - 20) * 256; biasp = b_v + (nt - 20) * 256;
                            sel = 2; dstkv = kv_v; lcol0 = (nt - 20) * 256; }
    } else {
        BT = BqT; bcol0 = nt * 256;
    }

    auto stage = [&](int n) {
        if (n >= 256) return;
        const int T = n >> 2, j = n & 3;
        const int buf = T & 1;
        const bool isA = (j == 0 || j == 3);
        const int half = (j == 0) ? 0 : (j == 3) ? 1 : (j - 1);
        const int k0 = T * 64;
        const bf16* g = isA ? (A + (size_t)(row0 + half * 128) * 4096)
                            : (BT + (size_t)(bcol0 + half * 128) * 4096);
        bf16* lb = &Lds[(isA ? 0 : 32768) + (buf * 2 + half) * 8192];
#pragma unroll
        for (int jj = 0; jj < 2; ++jj) {
            const int pc = (wv * 2 + jj) * 64 + lane;
            const int kk = pc >> 9, rem = pc & 511;
            const int row = rem >> 2, ccp = rem & 3;
            const int ccl = ccp ^ ((row >> 2) & 2);
            glds16(g + (size_t)row * 4096 + k0 + kk * 32 + ccl * 8,
                   lb + (wv * 2 + jj) * 512);
        }
    };

    const f32x4 vzero = {0.f, 0.f, 0.f, 0.f};
    f32x4 acc[8][4];
#pragma unroll
    for (int mi = 0; mi < 8; ++mi)
#pragma unroll
        for (int ni = 0; ni < 4; ++ni) acc[mi][ni] = vzero;

    bf16x8 a[4][2], b0[2][2], b1[2][2];

    for (int n = 0; n < 7; ++n) stage(n);
    asm volatile("s_waitcnt vmcnt(6)" ::: "memory");
    __builtin_amdgcn_s_barrier();

    for (int t = 0; t < 64; ++t) {
        const int buf = t & 1;
        const int nb = 4 * t;
        G256_LDA(a, buf, 0);
        G256_LDB(b0, buf, 0);
        stage(nb + 7);
        __builtin_amdgcn_s_barrier();
        G256_QUAD(a, b0, 0, 0);
        __builtin_amdgcn_s_barrier();
        G256_LDB(b1, buf, 1);
        stage(nb + 8);
        __builtin_amdgcn_s_barrier();
        G256_QUAD(a, b1, 0, 1);
        __builtin_amdgcn_s_barrier();
        G256_LDA(a, buf, 1);
        stage(nb + 9);
        __builtin_amdgcn_s_barrier();
        G256_QUAD(a, b0, 1, 0);
        __builtin_amdgcn_s_barrier();
        stage(nb + 10);
        __builtin_amdgcn_s_barrier();
        G256_QUAD(a, b1, 1, 1);
        if (t < 62)       asm volatile("s_waitcnt vmcnt(6)" ::: "memory");
        else if (t == 62) asm volatile("s_waitcnt vmcnt(0)" ::: "memory");
        __builtin_amdgcn_s_barrier();
    }

#pragma unroll
    for (int mi = 0; mi < 8; ++mi) {
        const int mtile = (mi >> 2) * 8 + (mi & 3) * 2 + wr;
#pragma unroll
        for (int ni = 0; ni < 4; ++ni) {
            const int ntile = ni * 4 + wc;
            const int gcl = ntile * 16 + l15;
#pragma unroll
            for (int i = 0; i < 4; ++i) {
                const int gr = row0 + mtile * 16 + quad * 4 + i;
                float vv = acc[mi][ni][i];
                if (EPI == 1) {
                    f_out[(size_t)gr * 4096 + ocol0 + gcl] = vv;
                } else {
                    vv += biasp[gcl];
                    if (sel == 0) {
                        q_out[(size_t)gr * 4096 + ocol0 + gcl] = (bf16)vv;
                    } else {
                        const int lc = lcol0 + gcl;
                        dstkv[(size_t)((gr >> 11) * 8 + (lc >> 7)) * 262144 +
                              (size_t)(gr & 2047) * 128 + (lc & 127)] = (bf16)vv;
                    }
                }
            }
        }
    }
}

// ---------------------------------------------------------------------------
// Fallback GEMM (m97 128^2) — only when workspace too small for hid_b.
// ---------------------------------------------------------------------------
template <int EPI, int AF32>
__global__ __launch_bounds__(256) void gemm_kernel(
    const float* __restrict__ A_f32, const bf16* __restrict__ A_bf16,
    const bf16* __restrict__ BqT, const bf16* __restrict__ BkT, const bf16* __restrict__ BvT,
    const float* __restrict__ b_q, const float* __restrict__ b_k, const float* __restrict__ b_v,
    bf16* __restrict__ q_out, bf16* __restrict__ kv_k, bf16* __restrict__ kv_v,
    float* __restrict__ f_out)
{
    constexpr int LDA = AF32 ? 34 : 32;
    __shared__ bf16 As[128 * LDA];
    __shared__ bf16 Bs[128 * 32];

    const int nt = blockIdx.x, mt = blockIdx.y;
    const int tid = threadIdx.x;
    const int wave = tid >> 6, lane = tid & 63;
    const int l15 = lane & 15, quad = lane >> 4;
    const int wm = (wave >> 1) * 64, wn = (wave & 1) * 64;

    const bf16* BT;
    const float* bias = nullptr;
    int sel = 0, ncol0;
    if (EPI == 0) {
        if (nt < 32)      { BT = BqT; bias = b_q; sel = 0; ncol0 = nt * 128; }
        else if (nt < 40) { BT = BkT; bias = b_k; sel = 1; ncol0 = (nt - 32) * 128; }
        else              { BT = BvT; bias = b_v; sel = 2; ncol0 = (nt - 40) * 128; }
    } else {
        BT = BqT; ncol0 = nt * 128;
    }
    const int row0 = mt * 128;

    const f32x4 vzero = {0.f, 0.f, 0.f, 0.f};
    f32x4 acc[4][4];
#pragma unroll
    for (int mi = 0; mi < 4; ++mi)
#pragma unroll
        for (int ni = 0; ni < 4; ++ni) acc[mi][ni] = vzero;

    const int a_row = tid >> 1, a_seg = (tid & 1) * 16;
    const int g_row = lane >> 2, g_seg = (lane & 3) * 8;

    for (int k0 = 0; k0 < 4096; k0 += 32) {
        if (AF32) {
            const float4* src = (const float4*)(A_f32 + (size_t)(row0 + a_row) * 4096 + k0 + a_seg);
            float4 f0 = src[0], f1 = src[1], f2 = src[2], f3 = src[3];
            bf16x8 p0, p1;
            p0[0] = (bf16)f0.x; p0[1] = (bf16)f0.y; p0[2] = (bf16)f0.z; p0[3] = (bf16)f0.w;
            p0[4] = (bf16)f1.x; p0[5] = (bf16)f1.y; p0[6] = (bf16)f1.z; p0[7] = (bf16)f1.w;
            p1[0] = (bf16)f2.x; p1[1] = (bf16)f2.y; p1[2] = (bf16)f2.z; p1[3] = (bf16)f2.w;
            p1[4] = (bf16)f3.x; p1[5] = (bf16)f3.y; p1[6] = (bf16)f3.z; p1[7] = (bf16)f3.w;
            *(bf16x8*)(&As[a_row * LDA + a_seg]) = p0;
            *(bf16x8*)(&As[a_row * LDA + a_seg + 8]) = p1;
        } else {
#pragma unroll
            for (int c = 0; c < 2; ++c)
                glds16(A_bf16 + (size_t)(row0 + wave * 32 + c * 16 + g_row) * 4096 + k0 + g_seg,
                       &As[(wave * 32 + c * 16) * 32]);
        }
#pragma unroll
        for (int c = 0; c < 2; ++c)
            glds16(BT + (size_t)(ncol0 + wave * 32 + c * 16 + g_row) * 4096 + k0 + g_seg,
                   &Bs[(wave * 32 + c * 16) * 32]);
        __syncthreads();

        bf16x8 af[4], bfv[4];
#pragma unroll
        for (int mi = 0; mi < 4; ++mi)
            af[mi] = *(const bf16x8*)(&As[(wm + mi * 16 + l15) * LDA + quad * 8]);
#pragma unroll
        for (int ni = 0; ni < 4; ++ni)
            bfv[ni] = *(const bf16x8*)(&Bs[(wn + ni * 16 + l15) * 32 + quad * 8]);
#pragma unroll
        for (int mi = 0; mi < 4; ++mi)
#pragma unroll
            for (int ni = 0; ni < 4; ++ni)
                acc[mi][ni] = __builtin_amdgcn_mfma_f32_16x16x32_bf16(af[mi], bfv[ni], acc[mi][ni], 0, 0, 0);
        __syncthreads();
    }

#pragma unroll
    for (int mi = 0; mi < 4; ++mi)
#pragma unroll
        for (int ni = 0; ni < 4; ++ni)
#pragma unroll
            for (int i = 0; i < 4; ++i) {
                const int gr = row0 + wm + mi * 16 + quad * 4 + i;
                const int gc = ncol0 + wn + ni * 16 + l15;
                float vv = acc[mi][ni][i];
                if (EPI == 1) {
                    f_out[(size_t)gr * 4096 + gc] = vv;
                } else {
                    vv += bias[gc];
                    if (sel == 0) {
                        q_out[(size_t)gr * 4096 + gc] = (bf16)vv;
                    } else {
                        bf16* dst = (sel == 1) ? kv_k : kv_v;
                        dst[(size_t)((gr >> 11) * 8 + (gc >> 7)) * 262144 +
                            (size_t)(gr & 2047) * 128 + (gc & 127)] = (bf16)vv;
                    }
                }
            }
}

// ---------------------------------------------------------------------------
// In-place RoPE. Q [b,s,h,128] (scale folded); K [b,kv,s,128].
// ---------------------------------------------------------------------------
__global__ __launch_bounds__(256) void rope_q_kernel(
    bf16* __restrict__ q, const int* __restrict__ pos_ids)
{
    const int idx = blockIdx.x * 256 + threadIdx.x;
    const int d = idx & 63, h = (idx >> 6) & 31, tok = idx >> 11;
    const float posv = (float)pos_ids[tok];
    const float fr = exp2f((float)d * (-19.931568569324174f / 64.f));
    float sn, cs;
    sincosf(posv * fr, &sn, &cs);
    bf16* xp = q + (size_t)tok * 4096 + h * 128 + d;
    const float x1 = (float)xp[0], x2 = (float)xp[64];
    const float scale = 0.08838834764831845f;
    xp[0]  = (bf16)((x1 * cs - x2 * sn) * scale);
    xp[64] = (bf16)((x1 * sn + x2 * cs) * scale);
}

__global__ __launch_bounds__(256) void rope_k_kernel(
    bf16* __restrict__ k, const int* __restrict__ pos_ids)
{
    const int idx = blockIdx.x * 256 + threadIdx.x;
    const int d = idx & 63, s = (idx >> 6) & 2047, bk = idx >> 17;
    const int b = bk >> 3;
    const float posv = (float)pos_ids[b * 2048 + s];
    const float fr = exp2f((float)d * (-19.931568569324174f / 64.f));
    float sn, cs;
    sincosf(posv * fr, &sn, &cs);
    bf16* xp = k + ((size_t)bk * 2048 + s) * 128 + d;
    const float x1 = (float)xp[0], x2 = (float)xp[64];
    xp[0]  = (bf16)(x1 * cs - x2 * sn);
    xp[64] = (bf16)(x1 * sn + x2 * cs);
}

// ---------------------------------------------------------------------------
// Flash attention, causal, GQA (R3 version: swapped-QK^T in-register softmax,
// defer-max, balanced q-tile pairs).
// ---------------------------------------------------------------------------
__global__ __launch_bounds__(256) void attn_kernel(
    const bf16* __restrict__ q, const bf16* __restrict__ k,
    const bf16* __restrict__ v, bf16* __restrict__ o)
{
    __shared__ bf16 Ksl[64 * 136];      // [kv][d]
    __shared__ bf16 Vsl[128 * 72];      // [d][kv]
    __shared__ bf16 Psl[4 * 16 * 68];   // per-wave [qrow][kv]

    const int pair = blockIdx.x & 7;
    const int h  = (blockIdx.x >> 3) & 31;
    const int b  = blockIdx.x >> 8;
    const int kvh = h >> 2;
    const int tid = threadIdx.x;
    const int wave = tid >> 6, lane = tid & 63;
    const int l15 = lane & 15, quad = lane >> 4;

    const bf16* kbase = k + (size_t)(b * 8 + kvh) * 2048 * 128;
    const bf16* vbase = v + (size_t)(b * 8 + kvh) * 2048 * 128;

    const int kr = tid >> 2, ksg = (tid & 3) * 32;
    const f32x4 vzero = {0.f, 0.f, 0.f, 0.f};

#pragma unroll 1
    for (int phase = 0; phase < 2; ++phase) {
        const int qt = phase ? (15 - pair) : pair;
        const int qbase = qt * 128 + wave * 32;

        bf16x8 qf[2][4];
#pragma unroll
        for (int mi = 0; mi < 2; ++mi) {
            const bf16* qrow = q + ((size_t)(b * 2048 + qbase + mi * 16 + l15) * 32 + h) * 128;
#pragma unroll
            for (int kb = 0; kb < 4; ++kb)
                qf[mi][kb] = *(const bf16x8*)(qrow + kb * 32 + quad * 8);
        }

        f32x4 acc_o[2][8];
#pragma unroll
        for (int mi = 0; mi < 2; ++mi)
#pragma unroll
            for (int i = 0; i < 8; ++i) acc_o[mi][i] = vzero;
        float m_i[2] = {-INFINITY, -INFINITY};
        float l_i[2] = {0.f, 0.f};

        const int nT = 2 * qt + 2;
        for (int t = 0; t < nT; ++t) {
            const int kv0 = t * 64;
            {
                const bf16x8* ks = (const bf16x8*)(kbase + (size_t)(kv0 + kr) * 128 + ksg);
                bf16x8* kd = (bf16x8*)(&Ksl[kr * 136 + ksg]);
                kd[0] = ks[0]; kd[1] = ks[1]; kd[2] = ks[2]; kd[3] = ks[3];
            }
            {
                const bf16x8* vs = (const bf16x8*)(vbase + (size_t)(kv0 + lane) * 128 + wave * 32);
                bf16x8 w0 = vs[0], w1 = vs[1], w2 = vs[2], w3 = vs[3];
#pragma unroll
                for (int i = 0; i < 8; ++i) {
                    Vsl[(wave * 32 + i)      * 72 + lane] = w0[i];
                    Vsl[(wave * 32 + 8 + i)  * 72 + lane] = w1[i];
                    Vsl[(wave * 32 + 16 + i) * 72 + lane] = w2[i];
                    Vsl[(wave * 32 + 24 + i) * 72 + lane] = w3[i];
                }
            }
            __syncthreads();

            if (kv0 <= qbase + 31) {
                f32x4 sacc[2][4];
#pragma unroll
                for (int mi = 0; mi < 2; ++mi)
#pragma unroll
                    for (int nt = 0; nt < 4; ++nt) sacc[mi][nt] = vzero;
                __builtin_amdgcn_s_setprio(1);
#pragma unroll
                for (int nt = 0; nt < 4; ++nt)
#pragma unroll
                    for (int kb = 0; kb < 4; ++kb) {
                        const bf16x8 kf = *(const bf16x8*)(&Ksl[(nt * 16 + l15) * 136 + kb * 32 + quad * 8]);
                        sacc[0][nt] = __builtin_amdgcn_mfma_f32_16x16x32_bf16(kf, qf[0][kb], sacc[0][nt], 0, 0, 0);
                        sacc[1][nt] = __builtin_amdgcn_mfma_f32_16x16x32_bf16(kf, qf[1][kb], sacc[1][nt], 0, 0, 0);
                    }
                __builtin_amdgcn_s_setprio(0);

                bf16x8 pf[2][2];
#pragma unroll
                for (int mi = 0; mi < 2; ++mi) {
                    const int rb = qbase + mi * 16;
                    if (kv0 + 63 > rb) {
#pragma unroll
                        for (int nt = 0; nt < 4; ++nt) {
                            const int kvr = kv0 + nt * 16 + quad * 4;
#pragma unroll
                            for (int i = 0; i < 4; ++i)
                                if (kvr + i > rb + l15) sacc[mi][nt][i] = -INFINITY;
                        }
                    }
                    float tm;
                    {
                        f32x4 m4;
#pragma unroll
                        for (int i = 0; i < 4; ++i)
                            m4[i] = fmaxf(fmaxf(sacc[mi][0][i], sacc[mi][1][i]),
                                          fmaxf(sacc[mi][2][i], sacc[mi][3][i]));
                        tm = fmaxf(fmaxf(m4[0], m4[1]), fmaxf(m4[2], m4[3]));
                        tm = fmaxf(tm, __shfl_xor(tm, 16, 64));
                        tm = fmaxf(tm, __shfl_xor(tm, 32, 64));
                    }
                    if (!__all(tm - m_i[mi] <= 8.f)) {
                        const float mnew = fmaxf(m_i[mi], tm);
                        const float alpha = __expf(m_i[mi] - mnew);
                        m_i[mi] = mnew;
                        l_i[mi] *= alpha;
                        float aw[4];
#pragma unroll
                        for (int i = 0; i < 4; ++i)
                            aw[i] = __shfl(alpha, quad * 4 + i, 16);
#pragma unroll
                        for (int dn = 0; dn < 8; ++dn)
#pragma unroll
                            for (int i = 0; i < 4; ++i) acc_o[mi][dn][i] *= aw[i];
                    }
                    float p[4][4];
                    float rs = 0.f;
#pragma unroll
                    for (int nt = 0; nt < 4; ++nt)
#pragma unroll
                        for (int i = 0; i < 4; ++i) {
                            p[nt][i] = __expf(sacc[mi][nt][i] - m_i[mi]);
                            rs += p[nt][i];
                        }
                    rs += __shfl_xor(rs, 16, 64);
                    rs += __shfl_xor(rs, 32, 64);
                    l_i[mi] += rs;
#pragma unroll
                    for (int nt = 0; nt < 4; ++nt) {
                        uint2 w;
                        w.x = cvt_pk_bf16(p[nt][0], p[nt][1]);
                        w.y = cvt_pk_bf16(p[nt][2], p[nt][3]);
                        *(uint2*)(&Psl[wave * 1088 + l15 * 68 + nt * 16 + quad * 4]) = w;
                    }
#pragma unroll
                    for (int k2 = 0; k2 < 2; ++k2)
                        pf[mi][k2] = *(const bf16x8*)(&Psl[wave * 1088 + l15 * 68 + k2 * 32 + quad * 8]);
                }

                __builtin_amdgcn_s_setprio(1);
#pragma unroll
                for (int dn = 0; dn < 8; ++dn)
#pragma unroll
                    for (int k2 = 0; k2 < 2; ++k2) {
                        const bf16x8 vf = *(const bf16x8*)(&Vsl[(dn * 16 + l15) * 72 + k2 * 32 + quad * 8]);
                        acc_o[0][dn] = __builtin_amdgcn_mfma_f32_16x16x32_bf16(pf[0][k2], vf, acc_o[0][dn], 0, 0, 0);
                        acc_o[1][dn] = __builtin_amdgcn_mfma_f32_16x16x32_bf16(pf[1][k2], vf, acc_o[1][dn], 0, 0, 0);
                    }
                __builtin_amdgcn_s_setprio(0);
            }
            __syncthreads();
        }

#pragma unroll
        for (int mi = 0; mi < 2; ++mi) {
            const float inv = 1.f / l_i[mi];
            float invw[4];
#pragma unroll
            for (int i = 0; i < 4; ++i)
                invw[i] = __shfl(inv, quad * 4 + i, 16);
#pragma unroll
            for (int dn = 0; dn < 8; ++dn)
#pragma unroll
                for (int i = 0; i < 4; ++i) {
                    const int s = qbase + mi * 16 + quad * 4 + i;
                    o[(((size_t)b * 2048 + s) * 32 + h) * 128 + dn * 16 + l15] =
                        (bf16)(acc_o[mi][dn][i] * invw[i]);
                }
        }
    }
}

// ---------------------------------------------------------------------------
extern "C" void kernel_launch(void* const* d_in, const int* in_sizes, int n_in,
                              void* d_out, int out_size, void* d_ws, size_t ws_size,
                              hipStream_t stream)
{
    (void)in_sizes; (void)n_in; (void)out_size;
    const float* hidden = (const float*)d_in[0];
    const int*   pos    = (const int*)d_in[1];
    const float* wq     = (const float*)d_in[2];
    const float* bq_    = (const float*)d_in[3];
    const float* wk     = (const float*)d_in[4];
    const float* bk_    = (const float*)d_in[5];
    const float* wv     = (const float*)d_in[6];
    const float* bv_    = (const float*)d_in[7];
    const float* wo     = (const float*)d_in[8];
    float* out = (float*)d_out;

    char* ws = (char*)d_ws;
    bf16* wqT   = (bf16*)(ws);                 // 33.5 MB -> attn_o after QKV
    bf16* wkT   = (bf16*)(ws + 33554432);      //  8.4 MB
    bf16* wvT   = (bf16*)(ws + 41943040);      //  8.4 MB
    bf16* q_pre = (bf16*)(ws + 50331648);      // 33.5 MB -> woT after attn
    bf16* k_t   = (bf16*)(ws + 83886080);      //  8.4 MB [b,kv,s,d]
    bf16* v_t   = (bf16*)(ws + 92274688);      //  8.4 MB [b,kv,s,d]
    bf16* hid_b = (bf16*)(ws + 100663296);     // 33.5 MB (if ws allows)
    bf16* attn_o = wqT;
    bf16* woT    = q_pre;
    const bool have_hid = (ws_size >= 134217728);

    // 1) weight transposes (fp32 [K][N] -> bf16 [N][K])
    transpose_conv_kernel<<<dim3(128, 64), 256, 0, stream>>>(wq, wqT, 4096);
    transpose_conv_kernel<<<dim3(32, 64), 256, 0, stream>>>(wk, wkT, 1024);
    transpose_conv_kernel<<<dim3(32, 64), 256, 0, stream>>>(wv, wvT, 1024);

    // 2) QKV projection; K/V written directly to [b,kv,s,d]
    if (have_hid) {
        convert_kernel<<<8192, 256, 0, stream>>>(hidden, hid_b);
        gemm_qkv_kernel<<<768, 512, 0, stream>>>(
            hid_b, wqT, wkT, wvT, bq_, bk_, bv_, q_pre, k_t, v_t);
    } else {
        gemm_kernel<0, 1><<<dim3(48, 32), 256, 0, stream>>>(
            hidden, nullptr, wqT, wkT, wvT, bq_, bk_, bv_, q_pre, k_t, v_t, nullptr);
    }

    // 3) in-place RoPE (Q gets 1/sqrt(128) folded)
    rope_q_kernel<<<32768, 256, 0, stream>>>(q_pre, pos);
    rope_k_kernel<<<8192, 256, 0, stream>>>(k_t, pos);

    // 4) causal GQA flash attention, balanced q-tile pairs -> attn_o [b,s,h,d]
    attn_kernel<<<512, 256, 0, stream>>>(q_pre, k_t, v_t, attn_o);

    // 5) transpose wo into q_pre region (q dead after attn)
    transpose_conv_kernel<<<dim3(128, 64), 256, 0, stream>>>(wo, woT, 4096);

    // 6) output projection -> d_out (fp32); 256 blocks = exactly 1 round
    if (have_hid) {
        gemm256_kernel<1><<<256, 512, 0, stream>>>(
            attn_o, woT, nullptr, nullptr, nullptr, nullptr, nullptr,
            nullptr, nullptr, nullptr, out, 256);
    } else {
        gemm_kernel<1, 0><<<dim3(32, 32), 256, 0, stream>>>(
            nullptr, attn_o, woT, nullptr, nullptr, nullptr, nullptr, nullptr,
            nullptr, nullptr, nullptr, out);
    }
}